// Round 2
// baseline (1238.807 us; speedup 1.0000x reference)
//
#include <hip/hip_runtime.h>

typedef unsigned short u16;
typedef __bf16 bf16x8 __attribute__((ext_vector_type(8)));
typedef float f32x4 __attribute__((ext_vector_type(4)));

__device__ __forceinline__ u16 f2bf(float f) {
  unsigned int u = __float_as_uint(f);
  u += 0x7fffu + ((u >> 16) & 1u);   // RNE
  return (u16)(u >> 16);
}
__device__ __forceinline__ float bf2f(u16 h) {
  return __uint_as_float(((unsigned int)h) << 16);
}
__device__ __forceinline__ float gelu_tanh(float x) {
  float u = 0.7978845608028654f * (x + 0.044715f * x * x * x);
  float e = __expf(-2.0f * fabsf(u));
  float t = (1.0f - e) / (1.0f + e);
  t = (u >= 0.0f) ? t : -t;
  return 0.5f * x * (1.0f + t);
}
__device__ __forceinline__ f32x4 mfma16(bf16x8 a, bf16x8 b, f32x4 c) {
  return __builtin_amdgcn_mfma_f32_16x16x32_bf16(a, b, c, 0, 0, 0);
}

// ---------------- modulation: out = silu(vec) @ W + b, 6144 cols ----------------
__global__ __launch_bounds__(256) void modulation_kernel(
    const float* __restrict__ vec,
    const float* __restrict__ w_o, const float* __restrict__ b_o,
    const float* __restrict__ w_c, const float* __restrict__ b_c,
    float* __restrict__ o_mod, float* __restrict__ c_mod) {
  __shared__ float sv[1024];
  const int tid = threadIdx.x;
  const bool isobs = blockIdx.x < 24;
  const float* w = isobs ? w_o : w_c;
  const float* b = isobs ? b_o : b_c;
  float* out = isobs ? o_mod : c_mod;
  const int j = (isobs ? blockIdx.x : blockIdx.x - 24) * 256 + tid;
  for (int i = tid; i < 1024; i += 256) {
    float v = vec[i];
    sv[i] = v / (1.0f + __expf(-v));
  }
  __syncthreads();
  float acc = 0.0f;
  for (int k = 0; k < 1024; ++k) acc += sv[k] * w[(size_t)k * 6144 + j];
  out[j] = acc + b[j];
}

// ------------- LayerNorm + (1+scale)*y + shift -> bf16 ; rows: cond first -------------
__global__ __launch_bounds__(256) void ln_mod_kernel(
    const float* __restrict__ xc, const float* __restrict__ xo,
    const float* __restrict__ modc, const float* __restrict__ modo,
    int mod_off, u16* __restrict__ out) {
  const int row = blockIdx.x, tid = threadIdx.x;
  const bool is_c = row < 1024;
  const float* x = is_c ? (xc + (size_t)row * 1024) : (xo + (size_t)(row - 1024) * 1024);
  const float* mod = (is_c ? modc : modo) + mod_off;
  float4 v = *(const float4*)(x + tid * 4);
  float s1 = v.x + v.y + v.z + v.w;
  float s2 = v.x * v.x + v.y * v.y + v.z * v.z + v.w * v.w;
#pragma unroll
  for (int m = 1; m < 64; m <<= 1) {
    s1 += __shfl_xor(s1, m);
    s2 += __shfl_xor(s2, m);
  }
  __shared__ float red[8];
  const int w = tid >> 6;
  if ((tid & 63) == 0) { red[w] = s1; red[4 + w] = s2; }
  __syncthreads();
  s1 = red[0] + red[1] + red[2] + red[3];
  s2 = red[4] + red[5] + red[6] + red[7];
  const float mean = s1 * (1.0f / 1024.0f);
  const float var = s2 * (1.0f / 1024.0f) - mean * mean;
  const float rstd = rsqrtf(var + 1e-6f);
  const int d = tid * 4;
  float vv[4] = {v.x, v.y, v.z, v.w};
  ushort4 ov;
  u16* po = (u16*)&ov;
#pragma unroll
  for (int i = 0; i < 4; ++i) {
    float y = (vv[i] - mean) * rstd;
    po[i] = f2bf((1.0f + mod[1024 + d + i]) * y + mod[d + i]);
  }
  *(ushort4*)(out + (size_t)row * 1024 + d) = ov;
}

// ---------------- GEMM: C = A(bf16,[M,K]) @ B(f32,[K,N]) , 128x128x32 tiles ----------------
// mode 0: store bf16       (qkv)
// mode 1: x1 = x0 + gate*(acc+bias)  f32   (proj, N=1024)
// mode 2: store bf16 gelu(acc+bias)  (mlp1)
// mode 3: d_out = x1 + gate*(acc+bias) with cond/obs row remap (mlp2, N=1024)
__global__ __launch_bounds__(256) void gemm_bf16(
    const u16* __restrict__ A, const float* __restrict__ Bc, const float* __restrict__ Bo,
    int M, int N, int K, int mode,
    const float* __restrict__ bias_c, const float* __restrict__ bias_o,
    const float* __restrict__ gate_c, const float* __restrict__ gate_o,
    const float* __restrict__ x0_c, const float* __restrict__ x0_o,
    const float* __restrict__ x1, void* __restrict__ outp) {
  __shared__ u16 As[128 * 40];  // [m][k] pad k to 40 (+16B) keeps 16B align, 2-way banks (free)
  __shared__ u16 Bs[128 * 40];  // [n][k] (B^T tile)
  const int tid = threadIdx.x;
  const int m0 = blockIdx.y * 128, n0 = blockIdx.x * 128;
  const bool is_c = (m0 < 1024);
  const float* __restrict__ B = is_c ? Bc : Bo;
  const int w = tid >> 6, lane = tid & 63, quad = lane >> 4, ln = lane & 15;
  const int wm = (w >> 1) * 64, wn = (w & 1) * 64;
  f32x4 acc[4][4] = {};
  const int nkt = K >> 5;
  for (int kt = 0; kt < nkt; ++kt) {
    __syncthreads();
#pragma unroll
    for (int st = 0; st < 2; ++st) {            // A tile 128x32 bf16
      int c = tid + st * 256;
      int row = c >> 2, k0 = (c & 3) << 3;
      *(uint4*)(As + row * 40 + k0) =
          *(const uint4*)(A + (size_t)(m0 + row) * K + kt * 32 + k0);
    }
#pragma unroll
    for (int st = 0; st < 4; ++st) {            // B tile 32x128 f32 -> bf16 transposed
      int c = tid + st * 256;
      int k = c >> 5, nn = (c & 31) << 2;
      float4 v = *(const float4*)(B + (size_t)(kt * 32 + k) * N + n0 + nn);
      Bs[(nn + 0) * 40 + k] = f2bf(v.x);
      Bs[(nn + 1) * 40 + k] = f2bf(v.y);
      Bs[(nn + 2) * 40 + k] = f2bf(v.z);
      Bs[(nn + 3) * 40 + k] = f2bf(v.w);
    }
    __syncthreads();
    bf16x8 a[4], b[4];
#pragma unroll
    for (int i = 0; i < 4; ++i)
      a[i] = *(const bf16x8*)(As + (wm + i * 16 + ln) * 40 + quad * 8);
#pragma unroll
    for (int j = 0; j < 4; ++j)
      b[j] = *(const bf16x8*)(Bs + (wn + j * 16 + ln) * 40 + quad * 8);
#pragma unroll
    for (int i = 0; i < 4; ++i)
#pragma unroll
      for (int j = 0; j < 4; ++j) acc[i][j] = mfma16(a[i], b[j], acc[i][j]);
  }
  const float* bias = is_c ? bias_c : bias_o;
  const float* gate = is_c ? gate_c : gate_o;
  const float* x0 = is_c ? x0_c : x0_o;
#pragma unroll
  for (int i = 0; i < 4; ++i) {
#pragma unroll
    for (int j = 0; j < 4; ++j) {
#pragma unroll
      for (int r = 0; r < 4; ++r) {
        const int row = m0 + wm + i * 16 + quad * 4 + r;   // C: col=lane&15, row=quad*4+r (m89/m91)
        const int col = n0 + wn + j * 16 + ln;
        const float v = acc[i][j][r];
        if (mode == 0) {
          ((u16*)outp)[(size_t)row * N + col] = f2bf(v);
        } else if (mode == 1) {
          const float xv = is_c ? x0[(size_t)row * 1024 + col]
                                : x0[(size_t)(row - 1024) * 1024 + col];
          ((float*)outp)[(size_t)row * 1024 + col] = xv + gate[col] * (v + bias[col]);
        } else if (mode == 2) {
          ((u16*)outp)[(size_t)row * N + col] = f2bf(gelu_tanh(v + bias[col]));
        } else {
          const float res = x1[(size_t)row * 1024 + col];
          const float val = res + gate[col] * (v + bias[col]);
          const size_t oidx = (row < 1024)
              ? (size_t)3145728 + (size_t)row * 1024 + col   // cond after obs in d_out
              : (size_t)(row - 1024) * 1024 + col;
          ((float*)outp)[oidx] = val;
        }
      }
    }
  }
}

// ---------------- qkv -> rmsnorm(q,k) + rope -> head-major bf16 q/k/v ----------------
__global__ __launch_bounds__(256) void qkvprep_kernel(
    const u16* __restrict__ qkv, const float* __restrict__ pe,
    const float* __restrict__ qs_c, const float* __restrict__ ks_c,
    const float* __restrict__ qs_o, const float* __restrict__ ks_o,
    u16* __restrict__ qh, u16* __restrict__ kh, u16* __restrict__ vh) {
  const int l = blockIdx.x, tid = threadIdx.x;
  const bool is_c = l < 1024;
  const float* qs = is_c ? qs_c : qs_o;
  const float* ks = is_c ? ks_c : ks_o;
  const int d = tid * 4, head = tid >> 4, dd = d & 63;
  const size_t hl = (size_t)head * 4096 + l;
  // pe broadcasts over heads: per-token 128 floats, pair index p = dd/2,
  // layout [pair][c][u] -> float offset p*4 = dd*2  (round-0 bug: used tid*8 -> OOB fault)
  const float* peb = pe + (size_t)l * 128 + (size_t)dd * 2;
  float4 pe0 = *(const float4*)(peb);
  float4 pe1 = *(const float4*)(peb + 4);
  {  // q
    ushort4 raw = *(const ushort4*)(qkv + (size_t)l * 3072 + d);
    float x0 = bf2f(raw.x), x1v = bf2f(raw.y), x2 = bf2f(raw.z), x3 = bf2f(raw.w);
    float ssq = x0 * x0 + x1v * x1v + x2 * x2 + x3 * x3;
#pragma unroll
    for (int m = 1; m < 16; m <<= 1) ssq += __shfl_xor(ssq, m);
    float rms = rsqrtf(ssq * (1.0f / 64.0f) + 1e-6f);
    float n0 = x0 * rms * qs[dd + 0], n1 = x1v * rms * qs[dd + 1];
    float n2 = x2 * rms * qs[dd + 2], n3 = x3 * rms * qs[dd + 3];
    ushort4 ov;
    ov.x = f2bf(pe0.x * n0 + pe0.y * n1);
    ov.y = f2bf(pe0.z * n0 + pe0.w * n1);
    ov.z = f2bf(pe1.x * n2 + pe1.y * n3);
    ov.w = f2bf(pe1.z * n2 + pe1.w * n3);
    *(ushort4*)(qh + hl * 64 + dd) = ov;
  }
  {  // k
    ushort4 raw = *(const ushort4*)(qkv + (size_t)l * 3072 + 1024 + d);
    float x0 = bf2f(raw.x), x1v = bf2f(raw.y), x2 = bf2f(raw.z), x3 = bf2f(raw.w);
    float ssq = x0 * x0 + x1v * x1v + x2 * x2 + x3 * x3;
#pragma unroll
    for (int m = 1; m < 16; m <<= 1) ssq += __shfl_xor(ssq, m);
    float rms = rsqrtf(ssq * (1.0f / 64.0f) + 1e-6f);
    float n0 = x0 * rms * ks[dd + 0], n1 = x1v * rms * ks[dd + 1];
    float n2 = x2 * rms * ks[dd + 2], n3 = x3 * rms * ks[dd + 3];
    ushort4 ov;
    ov.x = f2bf(pe0.x * n0 + pe0.y * n1);
    ov.y = f2bf(pe0.z * n0 + pe0.w * n1);
    ov.z = f2bf(pe1.x * n2 + pe1.y * n3);
    ov.w = f2bf(pe1.z * n2 + pe1.w * n3);
    *(ushort4*)(kh + hl * 64 + dd) = ov;
  }
  {  // v passthrough
    ushort4 raw = *(const ushort4*)(qkv + (size_t)l * 3072 + 2048 + d);
    *(ushort4*)(vh + hl * 64 + dd) = raw;
  }
}

// ---------------- flash attention, 64-q-row x 64-key tiles, online softmax ----------------
__global__ __launch_bounds__(256) void attn_kernel(
    const u16* __restrict__ qh, const u16* __restrict__ kh,
    const u16* __restrict__ vh, u16* __restrict__ attn) {
  constexpr int L = 4096;
  const int h = blockIdx.y;
  const int q0 = blockIdx.x * 64;
  const int tid = threadIdx.x, w = tid >> 6, lane = tid & 63;
  const int quad = lane >> 4, ln = lane & 15;
  const int wq = w * 16;
  __shared__ u16 Qs[64 * 72], Ks[64 * 72], Vt[64 * 72], Ps[64 * 72];
  {
    const u16* qb = qh + ((size_t)h * L + q0) * 64;
#pragma unroll
    for (int st = 0; st < 2; ++st) {
      int c = tid + st * 256;
      int row = c >> 3, d0 = (c & 7) << 3;
      *(uint4*)(Qs + row * 72 + d0) = *(const uint4*)(qb + row * 64 + d0);
    }
  }
  float mrow[4], lrow[4], alpha[4];
  f32x4 o[4] = {};
#pragma unroll
  for (int r = 0; r < 4; ++r) { mrow[r] = -1e30f; lrow[r] = 0.0f; }

  for (int kt = 0; kt < 64; ++kt) {
    __syncthreads();
    const u16* kb = kh + ((size_t)h * L + kt * 64) * 64;
    const u16* vb = vh + ((size_t)h * L + kt * 64) * 64;
#pragma unroll
    for (int st = 0; st < 2; ++st) {
      int c = tid + st * 256;
      int row = c >> 3, d0 = (c & 7) << 3;
      *(uint4*)(Ks + row * 72 + d0) = *(const uint4*)(kb + row * 64 + d0);
      uint4 vv = *(const uint4*)(vb + row * 64 + d0);
      const u16* ve = (const u16*)&vv;
#pragma unroll
      for (int e = 0; e < 8; ++e) Vt[(d0 + e) * 72 + row] = ve[e];  // V^T in LDS
    }
    __syncthreads();
    f32x4 s[4] = {};
    bf16x8 aq0 = *(const bf16x8*)(Qs + (wq + ln) * 72 + quad * 8);
    bf16x8 aq1 = *(const bf16x8*)(Qs + (wq + ln) * 72 + 32 + quad * 8);
#pragma unroll
    for (int j = 0; j < 4; ++j) {
      bf16x8 b0 = *(const bf16x8*)(Ks + (j * 16 + ln) * 72 + quad * 8);
      bf16x8 b1 = *(const bf16x8*)(Ks + (j * 16 + ln) * 72 + 32 + quad * 8);
      s[j] = mfma16(aq0, b0, s[j]);
      s[j] = mfma16(aq1, b1, s[j]);
    }
#pragma unroll
    for (int j = 0; j < 4; ++j)
#pragma unroll
      for (int r = 0; r < 4; ++r) s[j][r] *= 0.125f;  // Dh^-0.5
#pragma unroll
    for (int r = 0; r < 4; ++r) {
      float mx = fmaxf(fmaxf(s[0][r], s[1][r]), fmaxf(s[2][r], s[3][r]));
#pragma unroll
      for (int msk = 1; msk < 16; msk <<= 1) mx = fmaxf(mx, __shfl_xor(mx, msk));
      float mn = fmaxf(mrow[r], mx);
      alpha[r] = __expf(mrow[r] - mn);
      mrow[r] = mn;
    }
    float rs[4] = {0.f, 0.f, 0.f, 0.f};
#pragma unroll
    for (int j = 0; j < 4; ++j)
#pragma unroll
      for (int r = 0; r < 4; ++r) {
        float p = __expf(s[j][r] - mrow[r]);
        s[j][r] = p;
        rs[r] += p;
      }
#pragma unroll
    for (int r = 0; r < 4; ++r) {
#pragma unroll
      for (int msk = 1; msk < 16; msk <<= 1) rs[r] += __shfl_xor(rs[r], msk);
      lrow[r] = lrow[r] * alpha[r] + rs[r];
    }
#pragma unroll
    for (int jd = 0; jd < 4; ++jd)
#pragma unroll
      for (int r = 0; r < 4; ++r) o[jd][r] *= alpha[r];
    // P: C-layout -> LDS -> A-layout round trip (m120 pattern)
#pragma unroll
    for (int j = 0; j < 4; ++j)
#pragma unroll
      for (int r = 0; r < 4; ++r)
        Ps[(wq + quad * 4 + r) * 72 + j * 16 + ln] = f2bf(s[j][r]);
    __syncthreads();
    bf16x8 ap0 = *(const bf16x8*)(Ps + (wq + ln) * 72 + quad * 8);
    bf16x8 ap1 = *(const bf16x8*)(Ps + (wq + ln) * 72 + 32 + quad * 8);
#pragma unroll
    for (int jd = 0; jd < 4; ++jd) {
      bf16x8 v0 = *(const bf16x8*)(Vt + (jd * 16 + ln) * 72 + quad * 8);
      bf16x8 v1 = *(const bf16x8*)(Vt + (jd * 16 + ln) * 72 + 32 + quad * 8);
      o[jd] = mfma16(ap0, v0, o[jd]);
      o[jd] = mfma16(ap1, v1, o[jd]);
    }
  }
#pragma unroll
  for (int jd = 0; jd < 4; ++jd)
#pragma unroll
    for (int r = 0; r < 4; ++r) {
      const int row = q0 + wq + quad * 4 + r;
      attn[(size_t)row * 1024 + h * 64 + jd * 16 + ln] = f2bf(o[jd][r] / lrow[r]);
    }
}

extern "C" void kernel_launch(void* const* d_in, const int* in_sizes, int n_in,
                              void* d_out, int out_size, void* d_ws, size_t ws_size,
                              hipStream_t stream) {
  (void)in_sizes; (void)n_in; (void)out_size; (void)ws_size;
  const float* obs         = (const float*)d_in[0];
  const float* cond        = (const float*)d_in[1];
  const float* vec         = (const float*)d_in[2];
  const float* pe          = (const float*)d_in[3];
  const float* obs_mod_w   = (const float*)d_in[4];
  const float* obs_mod_b   = (const float*)d_in[5];
  const float* obs_qkv_w   = (const float*)d_in[6];
  const float* obs_q_scale = (const float*)d_in[7];
  const float* obs_k_scale = (const float*)d_in[8];
  const float* obs_proj_w  = (const float*)d_in[9];
  const float* obs_proj_b  = (const float*)d_in[10];
  const float* obs_mlp_w1  = (const float*)d_in[11];
  const float* obs_mlp_b1  = (const float*)d_in[12];
  const float* obs_mlp_w2  = (const float*)d_in[13];
  const float* obs_mlp_b2  = (const float*)d_in[14];
  const float* cond_mod_w  = (const float*)d_in[15];
  const float* cond_mod_b  = (const float*)d_in[16];
  const float* cond_qkv_w  = (const float*)d_in[17];
  const float* cond_q_scale= (const float*)d_in[18];
  const float* cond_k_scale= (const float*)d_in[19];
  const float* cond_proj_w = (const float*)d_in[20];
  const float* cond_proj_b = (const float*)d_in[21];
  const float* cond_mlp_w1 = (const float*)d_in[22];
  const float* cond_mlp_b1 = (const float*)d_in[23];
  const float* cond_mlp_w2 = (const float*)d_in[24];
  const float* cond_mlp_b2 = (const float*)d_in[25];

  // Compact liveness-aliased workspace, peak ~64.1 MB:
  //   [64K .. 64K+24M)   qkv (step3-4)            -> attn(8M)+x1(16M) (steps 5-9)
  //   [64K+24M .. +32M)  xm (steps 2-3)           -> hm (steps 7-8, first 8M of qh region)
  //   [64K+24M .. +48M)  qh/kh/vh (steps 4-5)
  //   [64K+32M .. +64M)  g (steps 8-9, overlaps kh/vh after they die)
  char* ws = (char*)d_ws;
  float* o_mod = (float*)ws;                       // 6144 f32
  float* c_mod = o_mod + 6144;                     // 6144 f32
  char* base   = ws + 65536;
  u16*  qkv  = (u16*)base;                         // [4096][3072] bf16, 24 MB
  u16*  attn = (u16*)base;                         // [4096][1024] bf16, 8 MB (after qkv dead)
  float* x1  = (float*)(base + 8388608);           // [4096][1024] f32, 16 MB
  u16*  xm   = (u16*)(base + 25165824);            // [4096][1024] bf16, 8 MB
  u16*  qh   = (u16*)(base + 25165824);            // [16][4096][64] bf16 ×3, 24 MB (after xm dead)
  u16*  kh   = qh + 4194304;
  u16*  vh   = kh + 4194304;
  u16*  hm   = (u16*)(base + 25165824);            // [4096][1024] bf16 (after qh dead)
  u16*  g    = (u16*)(base + 33554432);            // [4096][4096] bf16, 32 MB (after kh/vh dead)

  modulation_kernel<<<48, 256, 0, stream>>>(vec, obs_mod_w, obs_mod_b,
                                            cond_mod_w, cond_mod_b, o_mod, c_mod);
  ln_mod_kernel<<<4096, 256, 0, stream>>>(cond, obs, c_mod, o_mod, 0, xm);
  gemm_bf16<<<dim3(24, 32), 256, 0, stream>>>(xm, cond_qkv_w, obs_qkv_w, 4096, 3072, 1024, 0,
      nullptr, nullptr, nullptr, nullptr, nullptr, nullptr, nullptr, (void*)qkv);
  qkvprep_kernel<<<4096, 256, 0, stream>>>(qkv, pe, cond_q_scale, cond_k_scale,
                                           obs_q_scale, obs_k_scale, qh, kh, vh);
  attn_kernel<<<dim3(64, 16), 256, 0, stream>>>(qh, kh, vh, attn);
  gemm_bf16<<<dim3(8, 32), 256, 0, stream>>>(attn, cond_proj_w, obs_proj_w, 4096, 1024, 1024, 1,
      cond_proj_b, obs_proj_b, c_mod + 2048, o_mod + 2048, cond, obs, nullptr, (void*)x1);
  ln_mod_kernel<<<4096, 256, 0, stream>>>(x1, x1 + 1048576, c_mod, o_mod, 3072, hm);
  gemm_bf16<<<dim3(32, 32), 256, 0, stream>>>(hm, cond_mlp_w1, obs_mlp_w1, 4096, 4096, 1024, 2,
      cond_mlp_b1, obs_mlp_b1, nullptr, nullptr, nullptr, nullptr, nullptr, (void*)g);
  gemm_bf16<<<dim3(8, 32), 256, 0, stream>>>(g, cond_mlp_w2, obs_mlp_w2, 4096, 1024, 4096, 3,
      cond_mlp_b2, obs_mlp_b2, c_mod + 5120, o_mod + 5120, nullptr, nullptr, x1, (void*)d_out);
}

// Round 3
// 1130.297 us; speedup vs baseline: 1.0960x; 1.0960x over previous
//
#include <hip/hip_runtime.h>

typedef unsigned short u16;
typedef __bf16 bf16x8 __attribute__((ext_vector_type(8)));
typedef __bf16 bf16x4 __attribute__((ext_vector_type(4)));
typedef float f32x4 __attribute__((ext_vector_type(4)));

__device__ __forceinline__ u16 f2bf(float f) {
  unsigned int u = __float_as_uint(f);
  u += 0x7fffu + ((u >> 16) & 1u);   // RNE
  return (u16)(u >> 16);
}
__device__ __forceinline__ float bf2f(u16 h) {
  return __uint_as_float(((unsigned int)h) << 16);
}
__device__ __forceinline__ float gelu_tanh(float x) {
  float u = 0.7978845608028654f * (x + 0.044715f * x * x * x);
  float e = __expf(-2.0f * fabsf(u));
  float t = (1.0f - e) / (1.0f + e);
  t = (u >= 0.0f) ? t : -t;
  return 0.5f * x * (1.0f + t);
}
__device__ __forceinline__ f32x4 mfma16(bf16x8 a, bf16x8 b, f32x4 c) {
  return __builtin_amdgcn_mfma_f32_16x16x32_bf16(a, b, c, 0, 0, 0);
}
// two b64 LDS reads -> bf16x8 (for 68-u16-padded rows: 8B- but not 16B-aligned)
__device__ __forceinline__ bf16x8 ld8u(const u16* p) {
  bf16x4 a = *(const bf16x4*)p;
  bf16x4 b = *(const bf16x4*)(p + 4);
  return __builtin_shufflevector(a, b, 0, 1, 2, 3, 4, 5, 6, 7);
}

// ---------------- modulation: out = silu(vec) @ W + b, 6144 cols ----------------
__global__ __launch_bounds__(256) void modulation_kernel(
    const float* __restrict__ vec,
    const float* __restrict__ w_o, const float* __restrict__ b_o,
    const float* __restrict__ w_c, const float* __restrict__ b_c,
    float* __restrict__ o_mod, float* __restrict__ c_mod) {
  __shared__ float sv[1024];
  const int tid = threadIdx.x;
  const bool isobs = blockIdx.x < 24;
  const float* w = isobs ? w_o : w_c;
  const float* b = isobs ? b_o : b_c;
  float* out = isobs ? o_mod : c_mod;
  const int j = (isobs ? blockIdx.x : blockIdx.x - 24) * 256 + tid;
  for (int i = tid; i < 1024; i += 256) {
    float v = vec[i];
    sv[i] = v / (1.0f + __expf(-v));
  }
  __syncthreads();
  float acc = 0.0f;
  for (int k = 0; k < 1024; ++k) acc += sv[k] * w[(size_t)k * 6144 + j];
  out[j] = acc + b[j];
}

// ------------- LayerNorm + (1+scale)*y + shift -> bf16 ; rows: cond first -------------
__global__ __launch_bounds__(256) void ln_mod_kernel(
    const float* __restrict__ xc, const float* __restrict__ xo,
    const float* __restrict__ modc, const float* __restrict__ modo,
    int mod_off, u16* __restrict__ out) {
  const int row = blockIdx.x, tid = threadIdx.x;
  const bool is_c = row < 1024;
  const float* x = is_c ? (xc + (size_t)row * 1024) : (xo + (size_t)(row - 1024) * 1024);
  const float* mod = (is_c ? modc : modo) + mod_off;
  float4 v = *(const float4*)(x + tid * 4);
  float s1 = v.x + v.y + v.z + v.w;
  float s2 = v.x * v.x + v.y * v.y + v.z * v.z + v.w * v.w;
#pragma unroll
  for (int m = 1; m < 64; m <<= 1) {
    s1 += __shfl_xor(s1, m);
    s2 += __shfl_xor(s2, m);
  }
  __shared__ float red[8];
  const int w = tid >> 6;
  if ((tid & 63) == 0) { red[w] = s1; red[4 + w] = s2; }
  __syncthreads();
  s1 = red[0] + red[1] + red[2] + red[3];
  s2 = red[4] + red[5] + red[6] + red[7];
  const float mean = s1 * (1.0f / 1024.0f);
  const float var = s2 * (1.0f / 1024.0f) - mean * mean;
  const float rstd = rsqrtf(var + 1e-6f);
  const int d = tid * 4;
  float vv[4] = {v.x, v.y, v.z, v.w};
  ushort4 ov;
  u16* po = (u16*)&ov;
#pragma unroll
  for (int i = 0; i < 4; ++i) {
    float y = (vv[i] - mean) * rstd;
    po[i] = f2bf((1.0f + mod[1024 + d + i]) * y + mod[d + i]);
  }
  *(ushort4*)(out + (size_t)row * 1024 + d) = ov;
}

// ---------------- GEMM: C = A(bf16,[M,K]) @ B(f32,[K,N]) , 128x128x32 tiles ----------------
__global__ __launch_bounds__(256) void gemm_bf16(
    const u16* __restrict__ A, const float* __restrict__ Bc, const float* __restrict__ Bo,
    int M, int N, int K, int mode,
    const float* __restrict__ bias_c, const float* __restrict__ bias_o,
    const float* __restrict__ gate_c, const float* __restrict__ gate_o,
    const float* __restrict__ x0_c, const float* __restrict__ x0_o,
    const float* __restrict__ x1, void* __restrict__ outp) {
  __shared__ u16 As[128 * 40];
  __shared__ u16 Bs[128 * 40];
  const int tid = threadIdx.x;
  const int m0 = blockIdx.y * 128, n0 = blockIdx.x * 128;
  const bool is_c = (m0 < 1024);
  const float* __restrict__ B = is_c ? Bc : Bo;
  const int w = tid >> 6, lane = tid & 63, quad = lane >> 4, ln = lane & 15;
  const int wm = (w >> 1) * 64, wn = (w & 1) * 64;
  f32x4 acc[4][4] = {};
  const int nkt = K >> 5;
  for (int kt = 0; kt < nkt; ++kt) {
    __syncthreads();
#pragma unroll
    for (int st = 0; st < 2; ++st) {            // A tile 128x32 bf16
      int c = tid + st * 256;
      int row = c >> 2, k0 = (c & 3) << 3;
      *(uint4*)(As + row * 40 + k0) =
          *(const uint4*)(A + (size_t)(m0 + row) * K + kt * 32 + k0);
    }
#pragma unroll
    for (int st = 0; st < 4; ++st) {            // B tile 32x128 f32 -> bf16 transposed
      int c = tid + st * 256;
      int k = c >> 5, nn = (c & 31) << 2;
      float4 v = *(const float4*)(B + (size_t)(kt * 32 + k) * N + n0 + nn);
      Bs[(nn + 0) * 40 + k] = f2bf(v.x);
      Bs[(nn + 1) * 40 + k] = f2bf(v.y);
      Bs[(nn + 2) * 40 + k] = f2bf(v.z);
      Bs[(nn + 3) * 40 + k] = f2bf(v.w);
    }
    __syncthreads();
    bf16x8 a[4], b[4];
#pragma unroll
    for (int i = 0; i < 4; ++i)
      a[i] = *(const bf16x8*)(As + (wm + i * 16 + ln) * 40 + quad * 8);
#pragma unroll
    for (int j = 0; j < 4; ++j)
      b[j] = *(const bf16x8*)(Bs + (wn + j * 16 + ln) * 40 + quad * 8);
#pragma unroll
    for (int i = 0; i < 4; ++i)
#pragma unroll
      for (int j = 0; j < 4; ++j) acc[i][j] = mfma16(a[i], b[j], acc[i][j]);
  }
  const float* bias = is_c ? bias_c : bias_o;
  const float* gate = is_c ? gate_c : gate_o;
  const float* x0 = is_c ? x0_c : x0_o;
#pragma unroll
  for (int i = 0; i < 4; ++i) {
#pragma unroll
    for (int j = 0; j < 4; ++j) {
#pragma unroll
      for (int r = 0; r < 4; ++r) {
        const int row = m0 + wm + i * 16 + quad * 4 + r;
        const int col = n0 + wn + j * 16 + ln;
        const float v = acc[i][j][r];
        if (mode == 0) {
          ((u16*)outp)[(size_t)row * N + col] = f2bf(v);
        } else if (mode == 1) {
          const float xv = is_c ? x0[(size_t)row * 1024 + col]
                                : x0[(size_t)(row - 1024) * 1024 + col];
          ((float*)outp)[(size_t)row * 1024 + col] = xv + gate[col] * (v + bias[col]);
        } else if (mode == 2) {
          ((u16*)outp)[(size_t)row * N + col] = f2bf(gelu_tanh(v + bias[col]));
        } else {
          const float res = x1[(size_t)row * 1024 + col];
          const float val = res + gate[col] * (v + bias[col]);
          const size_t oidx = (row < 1024)
              ? (size_t)3145728 + (size_t)row * 1024 + col
              : (size_t)(row - 1024) * 1024 + col;
          ((float*)outp)[oidx] = val;
        }
      }
    }
  }
}

// ---------------- qkv -> rmsnorm(q,k) + rope -> head-major bf16 q/k/v ----------------
__global__ __launch_bounds__(256) void qkvprep_kernel(
    const u16* __restrict__ qkv, const float* __restrict__ pe,
    const float* __restrict__ qs_c, const float* __restrict__ ks_c,
    const float* __restrict__ qs_o, const float* __restrict__ ks_o,
    u16* __restrict__ qh, u16* __restrict__ kh, u16* __restrict__ vh) {
  const int l = blockIdx.x, tid = threadIdx.x;
  const bool is_c = l < 1024;
  const float* qs = is_c ? qs_c : qs_o;
  const float* ks = is_c ? ks_c : ks_o;
  const int d = tid * 4, head = tid >> 4, dd = d & 63;
  const size_t hl = (size_t)head * 4096 + l;
  const float* peb = pe + (size_t)l * 128 + (size_t)dd * 2;  // head-broadcast rope
  float4 pe0 = *(const float4*)(peb);
  float4 pe1 = *(const float4*)(peb + 4);
  {  // q
    ushort4 raw = *(const ushort4*)(qkv + (size_t)l * 3072 + d);
    float x0 = bf2f(raw.x), x1v = bf2f(raw.y), x2 = bf2f(raw.z), x3 = bf2f(raw.w);
    float ssq = x0 * x0 + x1v * x1v + x2 * x2 + x3 * x3;
#pragma unroll
    for (int m = 1; m < 16; m <<= 1) ssq += __shfl_xor(ssq, m);
    float rms = rsqrtf(ssq * (1.0f / 64.0f) + 1e-6f);
    float n0 = x0 * rms * qs[dd + 0], n1 = x1v * rms * qs[dd + 1];
    float n2 = x2 * rms * qs[dd + 2], n3 = x3 * rms * qs[dd + 3];
    ushort4 ov;
    ov.x = f2bf(pe0.x * n0 + pe0.y * n1);
    ov.y = f2bf(pe0.z * n0 + pe0.w * n1);
    ov.z = f2bf(pe1.x * n2 + pe1.y * n3);
    ov.w = f2bf(pe1.z * n2 + pe1.w * n3);
    *(ushort4*)(qh + hl * 64 + dd) = ov;
  }
  {  // k
    ushort4 raw = *(const ushort4*)(qkv + (size_t)l * 3072 + 1024 + d);
    float x0 = bf2f(raw.x), x1v = bf2f(raw.y), x2 = bf2f(raw.z), x3 = bf2f(raw.w);
    float ssq = x0 * x0 + x1v * x1v + x2 * x2 + x3 * x3;
#pragma unroll
    for (int m = 1; m < 16; m <<= 1) ssq += __shfl_xor(ssq, m);
    float rms = rsqrtf(ssq * (1.0f / 64.0f) + 1e-6f);
    float n0 = x0 * rms * ks[dd + 0], n1 = x1v * rms * ks[dd + 1];
    float n2 = x2 * rms * ks[dd + 2], n3 = x3 * rms * ks[dd + 3];
    ushort4 ov;
    ov.x = f2bf(pe0.x * n0 + pe0.y * n1);
    ov.y = f2bf(pe0.z * n0 + pe0.w * n1);
    ov.z = f2bf(pe1.x * n2 + pe1.y * n3);
    ov.w = f2bf(pe1.z * n2 + pe1.w * n3);
    *(ushort4*)(kh + hl * 64 + dd) = ov;
  }
  {  // v passthrough
    ushort4 raw = *(const ushort4*)(qkv + (size_t)l * 3072 + 2048 + d);
    *(ushort4*)(vh + hl * 64 + dd) = raw;
  }
}

// ---------------- one-shot V transpose: vh[h][l][d] -> vt[h][d][l] ----------------
// Kills the 64x-redundant 16-way-conflict in-attn transpose (R2 post-mortem).
__global__ __launch_bounds__(256) void vtrans_kernel(
    const u16* __restrict__ vh, u16* __restrict__ vt) {
  const int h = blockIdx.y, k0 = blockIdx.x * 64;
  __shared__ u16 s[64 * 66];   // [key][dim], pad 66 -> ~2-way on scalar stores
  const int tid = threadIdx.x;
#pragma unroll
  for (int st = 0; st < 2; ++st) {
    int c = tid + st * 256;
    int row = c >> 3, off = (c & 7) << 3;      // row=key, off=dim
    ushort4 v0 = *(const ushort4*)(vh + ((size_t)h * 4096 + k0 + row) * 64 + off);
    ushort4 v1 = *(const ushort4*)(vh + ((size_t)h * 4096 + k0 + row) * 64 + off + 4);
    u16* p = s + row * 66 + off;
    p[0] = v0.x; p[1] = v0.y; p[2] = v0.z; p[3] = v0.w;
    p[4] = v1.x; p[5] = v1.y; p[6] = v1.z; p[7] = v1.w;
  }
  __syncthreads();
#pragma unroll
  for (int st = 0; st < 2; ++st) {
    int c = tid + st * 256;
    int dd = c >> 3, kk = (c & 7) << 3;        // dd=dim, kk=key offset
    ushort4 a, b;
    a.x = s[(kk + 0) * 66 + dd]; a.y = s[(kk + 1) * 66 + dd];
    a.z = s[(kk + 2) * 66 + dd]; a.w = s[(kk + 3) * 66 + dd];
    b.x = s[(kk + 4) * 66 + dd]; b.y = s[(kk + 5) * 66 + dd];
    b.z = s[(kk + 6) * 66 + dd]; b.w = s[(kk + 7) * 66 + dd];
    u16* o = vt + ((size_t)h * 64 + dd) * 4096 + k0 + kk;
    *(ushort4*)(o) = a;
    *(ushort4*)(o + 4) = b;
  }
}

// ---------------- flash attention v2: pre-transposed V, aliased Q/P LDS ----------------
__global__ __launch_bounds__(256) void attn_kernel(
    const u16* __restrict__ qh, const u16* __restrict__ kh,
    const u16* __restrict__ vt, u16* __restrict__ attn) {
  constexpr int L = 4096;
  const int h = blockIdx.y;
  const int q0 = blockIdx.x * 64;
  const int tid = threadIdx.x, w = tid >> 6, lane = tid & 63;
  const int quad = lane >> 4, ln = lane & 15;
  const int wq = w * 16;
  // QP: Q tile then (after frag hoist) per-wave-private P buffer. pad 68:
  //   P-write banks: quad stride 4*68 u16 = 136 dw = 8 mod 32 -> quads at 0/8/16/24,
  //   16 u16 = 8 dwords each -> disjoint, 2 lanes/dword = 2-way = free (m136).
  __shared__ u16 QP[64 * 68];
  __shared__ u16 Ks[64 * 72];   // [key][dim], 144B rows: b128-aligned, 2-way reads
  __shared__ u16 Vs[64 * 72];   // [dim][key] from vt: b128-aligned
  {
    const u16* qb = qh + ((size_t)h * L + q0) * 64;
#pragma unroll
    for (int st = 0; st < 2; ++st) {
      int c = tid + st * 256;
      int row = c >> 3, d0 = (c & 7) << 3;
      uint4 v = *(const uint4*)(qb + row * 64 + d0);
      *(uint2*)(QP + row * 68 + d0) = make_uint2(v.x, v.y);
      *(uint2*)(QP + row * 68 + d0 + 4) = make_uint2(v.z, v.w);
    }
  }
  __syncthreads();
  // hoist Q fragments (wave-private rows wq..wq+15)
  bf16x8 aq0 = ld8u(QP + (wq + ln) * 68 + quad * 8);
  bf16x8 aq1 = ld8u(QP + (wq + ln) * 68 + 32 + quad * 8);

  float mrow[4], lrow[4], alpha[4];
  f32x4 o[4] = {};
#pragma unroll
  for (int r = 0; r < 4; ++r) { mrow[r] = -1e30f; lrow[r] = 0.0f; }

  const u16* kbase = kh + (size_t)h * L * 64;
  const u16* vbase = vt + (size_t)h * 64 * L;
  for (int kt = 0; kt < 64; ++kt) {
    __syncthreads();   // Ks/Vs of previous tile fully consumed
#pragma unroll
    for (int st = 0; st < 2; ++st) {
      int c = tid + st * 256;
      int row = c >> 3, off = (c & 7) << 3;
      *(uint4*)(Ks + row * 72 + off) =
          *(const uint4*)(kbase + (size_t)(kt * 64 + row) * 64 + off);
      *(uint4*)(Vs + row * 72 + off) =
          *(const uint4*)(vbase + (size_t)row * L + kt * 64 + off);
    }
    __syncthreads();
    f32x4 s[4] = {};
#pragma unroll
    for (int j = 0; j < 4; ++j) {
      bf16x8 b0 = *(const bf16x8*)(Ks + (j * 16 + ln) * 72 + quad * 8);
      bf16x8 b1 = *(const bf16x8*)(Ks + (j * 16 + ln) * 72 + 32 + quad * 8);
      s[j] = mfma16(aq0, b0, s[j]);
      s[j] = mfma16(aq1, b1, s[j]);
    }
#pragma unroll
    for (int j = 0; j < 4; ++j)
#pragma unroll
      for (int r = 0; r < 4; ++r) s[j][r] *= 0.125f;
#pragma unroll
    for (int r = 0; r < 4; ++r) {
      float mx = fmaxf(fmaxf(s[0][r], s[1][r]), fmaxf(s[2][r], s[3][r]));
#pragma unroll
      for (int msk = 1; msk < 16; msk <<= 1) mx = fmaxf(mx, __shfl_xor(mx, msk));
      float mn = fmaxf(mrow[r], mx);
      alpha[r] = __expf(mrow[r] - mn);
      mrow[r] = mn;
    }
    float rs[4] = {0.f, 0.f, 0.f, 0.f};
#pragma unroll
    for (int j = 0; j < 4; ++j)
#pragma unroll
      for (int r = 0; r < 4; ++r) {
        float p = __expf(s[j][r] - mrow[r]);
        s[j][r] = p;
        rs[r] += p;
      }
#pragma unroll
    for (int r = 0; r < 4; ++r) {
#pragma unroll
      for (int msk = 1; msk < 16; msk <<= 1) rs[r] += __shfl_xor(rs[r], msk);
      lrow[r] = lrow[r] * alpha[r] + rs[r];
    }
#pragma unroll
    for (int jd = 0; jd < 4; ++jd)
#pragma unroll
      for (int r = 0; r < 4; ++r) o[jd][r] *= alpha[r];
    // P: C-layout -> wave-private LDS rows -> A-layout (no barrier needed)
#pragma unroll
    for (int j = 0; j < 4; ++j)
#pragma unroll
      for (int r = 0; r < 4; ++r)
        QP[(wq + quad * 4 + r) * 68 + j * 16 + ln] = f2bf(s[j][r]);
    bf16x8 ap0 = ld8u(QP + (wq + ln) * 68 + quad * 8);
    bf16x8 ap1 = ld8u(QP + (wq + ln) * 68 + 32 + quad * 8);
#pragma unroll
    for (int jd = 0; jd < 4; ++jd) {
      bf16x8 v0 = *(const bf16x8*)(Vs + (jd * 16 + ln) * 72 + quad * 8);
      bf16x8 v1 = *(const bf16x8*)(Vs + (jd * 16 + ln) * 72 + 32 + quad * 8);
      o[jd] = mfma16(ap0, v0, o[jd]);
      o[jd] = mfma16(ap1, v1, o[jd]);
    }
  }
#pragma unroll
  for (int jd = 0; jd < 4; ++jd)
#pragma unroll
    for (int r = 0; r < 4; ++r) {
      const int row = q0 + wq + quad * 4 + r;
      attn[(size_t)row * 1024 + h * 64 + jd * 16 + ln] = f2bf(o[jd][r] / lrow[r]);
    }
}

extern "C" void kernel_launch(void* const* d_in, const int* in_sizes, int n_in,
                              void* d_out, int out_size, void* d_ws, size_t ws_size,
                              hipStream_t stream) {
  (void)in_sizes; (void)n_in; (void)out_size; (void)ws_size;
  const float* obs         = (const float*)d_in[0];
  const float* cond        = (const float*)d_in[1];
  const float* vec         = (const float*)d_in[2];
  const float* pe          = (const float*)d_in[3];
  const float* obs_mod_w   = (const float*)d_in[4];
  const float* obs_mod_b   = (const float*)d_in[5];
  const float* obs_qkv_w   = (const float*)d_in[6];
  const float* obs_q_scale = (const float*)d_in[7];
  const float* obs_k_scale = (const float*)d_in[8];
  const float* obs_proj_w  = (const float*)d_in[9];
  const float* obs_proj_b  = (const float*)d_in[10];
  const float* obs_mlp_w1  = (const float*)d_in[11];
  const float* obs_mlp_b1  = (const float*)d_in[12];
  const float* obs_mlp_w2  = (const float*)d_in[13];
  const float* obs_mlp_b2  = (const float*)d_in[14];
  const float* cond_mod_w  = (const float*)d_in[15];
  const float* cond_mod_b  = (const float*)d_in[16];
  const float* cond_qkv_w  = (const float*)d_in[17];
  const float* cond_q_scale= (const float*)d_in[18];
  const float* cond_k_scale= (const float*)d_in[19];
  const float* cond_proj_w = (const float*)d_in[20];
  const float* cond_proj_b = (const float*)d_in[21];
  const float* cond_mlp_w1 = (const float*)d_in[22];
  const float* cond_mlp_b1 = (const float*)d_in[23];
  const float* cond_mlp_w2 = (const float*)d_in[24];
  const float* cond_mlp_b2 = (const float*)d_in[25];

  // Workspace liveness map (peak 64 MB + 64K):
  //   [0,64K)      o_mod/c_mod
  //   +0M..24M     qkv (steps 3-4)        -> attn(8M) + x1(16M) (steps 5-9)
  //   +24M..32M    xm (2-3)               -> qh (4-5) -> hm (7-8)
  //   +32M..48M    kh, vh (4-5)           -> g[32M] spans +32M..64M (8-9)
  //   +48M..56M    vt (4.5-5)             (dead before g is written)
  char* ws = (char*)d_ws;
  float* o_mod = (float*)ws;
  float* c_mod = o_mod + 6144;
  char* base   = ws + 65536;
  u16*  qkv  = (u16*)base;                         // 24 MB
  u16*  attn = (u16*)base;                         // 8 MB
  float* x1  = (float*)(base + 8388608);           // 16 MB
  u16*  xm   = (u16*)(base + 25165824);            // 8 MB
  u16*  qh   = (u16*)(base + 25165824);            // 8 MB
  u16*  kh   = (u16*)(base + 33554432);            // 8 MB
  u16*  vh   = (u16*)(base + 41943040);            // 8 MB
  u16*  vt   = (u16*)(base + 50331648);            // 8 MB  [16][64][4096]
  u16*  hm   = (u16*)(base + 25165824);            // 8 MB
  u16*  g    = (u16*)(base + 33554432);            // 32 MB

  modulation_kernel<<<48, 256, 0, stream>>>(vec, obs_mod_w, obs_mod_b,
                                            cond_mod_w, cond_mod_b, o_mod, c_mod);
  ln_mod_kernel<<<4096, 256, 0, stream>>>(cond, obs, c_mod, o_mod, 0, xm);
  gemm_bf16<<<dim3(24, 32), 256, 0, stream>>>(xm, cond_qkv_w, obs_qkv_w, 4096, 3072, 1024, 0,
      nullptr, nullptr, nullptr, nullptr, nullptr, nullptr, nullptr, (void*)qkv);
  qkvprep_kernel<<<4096, 256, 0, stream>>>(qkv, pe, cond_q_scale, cond_k_scale,
                                           obs_q_scale, obs_k_scale, qh, kh, vh);
  vtrans_kernel<<<dim3(64, 16), 256, 0, stream>>>(vh, vt);
  attn_kernel<<<dim3(64, 16), 256, 0, stream>>>(qh, kh, vt, attn);
  gemm_bf16<<<dim3(8, 32), 256, 0, stream>>>(attn, cond_proj_w, obs_proj_w, 4096, 1024, 1024, 1,
      cond_proj_b, obs_proj_b, c_mod + 2048, o_mod + 2048, cond, obs, nullptr, (void*)x1);
  ln_mod_kernel<<<4096, 256, 0, stream>>>(x1, x1 + 1048576, c_mod, o_mod, 3072, hm);
  gemm_bf16<<<dim3(32, 32), 256, 0, stream>>>(hm, cond_mlp_w1, obs_mlp_w1, 4096, 4096, 1024, 2,
      cond_mlp_b1, obs_mlp_b1, nullptr, nullptr, nullptr, nullptr, nullptr, (void*)g);
  gemm_bf16<<<dim3(8, 32), 256, 0, stream>>>(g, cond_mlp_w2, obs_mlp_w2, 4096, 1024, 4096, 3,
      cond_mlp_b2, obs_mlp_b2, c_mod + 5120, o_mod + 5120, nullptr, nullptr, x1, (void*)d_out);
}

// Round 4
// 679.075 us; speedup vs baseline: 1.8243x; 1.6645x over previous
//
#include <hip/hip_runtime.h>

typedef unsigned short u16;
typedef __bf16 bf16x8 __attribute__((ext_vector_type(8)));
typedef __bf16 bf16x4 __attribute__((ext_vector_type(4)));
typedef float f32x4 __attribute__((ext_vector_type(4)));

#define GLOAD_LDS16(g, l)                                                    \
  __builtin_amdgcn_global_load_lds(                                          \
      (const __attribute__((address_space(1))) void*)(g),                    \
      (__attribute__((address_space(3))) void*)(l), 16, 0, 0)

__device__ __forceinline__ u16 f2bf(float f) {
  unsigned int u = __float_as_uint(f);
  u += 0x7fffu + ((u >> 16) & 1u);   // RNE
  return (u16)(u >> 16);
}
__device__ __forceinline__ u16 f2bf_trunc(float f) {
  return (u16)(__float_as_uint(f) >> 16);
}
__device__ __forceinline__ float bf2f(u16 h) {
  return __uint_as_float(((unsigned int)h) << 16);
}
__device__ __forceinline__ float gelu_tanh(float x) {
  float u = 0.7978845608028654f * (x + 0.044715f * x * x * x);
  float e = __expf(-2.0f * fabsf(u));
  float t = (1.0f - e) / (1.0f + e);
  t = (u >= 0.0f) ? t : -t;
  return 0.5f * x * (1.0f + t);
}
__device__ __forceinline__ f32x4 mfma16(bf16x8 a, bf16x8 b, f32x4 c) {
  return __builtin_amdgcn_mfma_f32_16x16x32_bf16(a, b, c, 0, 0, 0);
}
__device__ __forceinline__ bf16x8 ld8u(const u16* p) {  // 8B-aligned bf16x8
  bf16x4 a = *(const bf16x4*)p;
  bf16x4 b = *(const bf16x4*)(p + 4);
  return __builtin_shufflevector(a, b, 0, 1, 2, 3, 4, 5, 6, 7);
}

// ---------------- modulation: out = silu(vec) @ W + b ----------------
__global__ __launch_bounds__(256) void modulation_kernel(
    const float* __restrict__ vec,
    const float* __restrict__ w_o, const float* __restrict__ b_o,
    const float* __restrict__ w_c, const float* __restrict__ b_c,
    float* __restrict__ o_mod, float* __restrict__ c_mod) {
  __shared__ float sv[1024];
  __shared__ float red[256];
  const int tid = threadIdx.x;
  const bool isobs = blockIdx.x < 96;
  const float* w = isobs ? w_o : w_c;
  const float* b = isobs ? b_o : b_c;
  float* out = isobs ? o_mod : c_mod;
  const int jb = (isobs ? blockIdx.x : blockIdx.x - 96) * 64;
  const int col = tid & 63, sl = tid >> 6;
  for (int i = tid; i < 1024; i += 256) {
    float v = vec[i];
    sv[i] = v / (1.0f + __expf(-v));
  }
  __syncthreads();
  float acc = 0.0f;
  const int kb = sl * 256;
  for (int k = 0; k < 256; ++k)
    acc += sv[kb + k] * w[(size_t)(kb + k) * 6144 + jb + col];
  red[tid] = acc;
  __syncthreads();
  if (sl == 0)
    out[jb + col] = red[col] + red[col + 64] + red[col + 128] + red[col + 192] + b[jb + col];
}

// ------------- LayerNorm + (1+scale)*y + shift -> bf16 ; rows: cond first -------------
__global__ __launch_bounds__(256) void ln_mod_kernel(
    const float* __restrict__ xc, const float* __restrict__ xo,
    const float* __restrict__ modc, const float* __restrict__ modo,
    int mod_off, u16* __restrict__ out) {
  const int row = blockIdx.x, tid = threadIdx.x;
  const bool is_c = row < 1024;
  const float* x = is_c ? (xc + (size_t)row * 1024) : (xo + (size_t)(row - 1024) * 1024);
  const float* mod = (is_c ? modc : modo) + mod_off;
  float4 v = *(const float4*)(x + tid * 4);
  float s1 = v.x + v.y + v.z + v.w;
  float s2 = v.x * v.x + v.y * v.y + v.z * v.z + v.w * v.w;
#pragma unroll
  for (int m = 1; m < 64; m <<= 1) {
    s1 += __shfl_xor(s1, m);
    s2 += __shfl_xor(s2, m);
  }
  __shared__ float red[8];
  const int w = tid >> 6;
  if ((tid & 63) == 0) { red[w] = s1; red[4 + w] = s2; }
  __syncthreads();
  s1 = red[0] + red[1] + red[2] + red[3];
  s2 = red[4] + red[5] + red[6] + red[7];
  const float mean = s1 * (1.0f / 1024.0f);
  const float var = s2 * (1.0f / 1024.0f) - mean * mean;
  const float rstd = rsqrtf(var + 1e-6f);
  const int d = tid * 4;
  float vv[4] = {v.x, v.y, v.z, v.w};
  ushort4 ov;
  u16* po = (u16*)&ov;
#pragma unroll
  for (int i = 0; i < 4; ++i) {
    float y = (vv[i] - mean) * rstd;
    po[i] = f2bf((1.0f + mod[1024 + d + i]) * y + mod[d + i]);
  }
  *(ushort4*)(out + (size_t)row * 1024 + d) = ov;
}

// ---- same, bf16 input (x1 residual stream) ----
__global__ __launch_bounds__(256) void ln_mod_b_kernel(
    const u16* __restrict__ x,
    const float* __restrict__ modc, const float* __restrict__ modo,
    int mod_off, u16* __restrict__ out) {
  const int row = blockIdx.x, tid = threadIdx.x;
  const bool is_c = row < 1024;
  const float* mod = (is_c ? modc : modo) + mod_off;
  ushort4 rv = *(const ushort4*)(x + (size_t)row * 1024 + tid * 4);
  float vv[4] = {bf2f(rv.x), bf2f(rv.y), bf2f(rv.z), bf2f(rv.w)};
  float s1 = vv[0] + vv[1] + vv[2] + vv[3];
  float s2 = vv[0] * vv[0] + vv[1] * vv[1] + vv[2] * vv[2] + vv[3] * vv[3];
#pragma unroll
  for (int m = 1; m < 64; m <<= 1) {
    s1 += __shfl_xor(s1, m);
    s2 += __shfl_xor(s2, m);
  }
  __shared__ float red[8];
  const int w = tid >> 6;
  if ((tid & 63) == 0) { red[w] = s1; red[4 + w] = s2; }
  __syncthreads();
  s1 = red[0] + red[1] + red[2] + red[3];
  s2 = red[4] + red[5] + red[6] + red[7];
  const float mean = s1 * (1.0f / 1024.0f);
  const float var = s2 * (1.0f / 1024.0f) - mean * mean;
  const float rstd = rsqrtf(var + 1e-6f);
  const int d = tid * 4;
  ushort4 ov;
  u16* po = (u16*)&ov;
#pragma unroll
  for (int i = 0; i < 4; ++i) {
    float y = (vv[i] - mean) * rstd;
    po[i] = f2bf((1.0f + mod[1024 + d + i]) * y + mod[d + i]);
  }
  *(ushort4*)(out + (size_t)row * 1024 + d) = ov;
}

// ---- weight pre-cast+transpose: src f32 [K][N] -> dst bf16 [N][K] ----
__global__ __launch_bounds__(256) void transcast_kernel(
    const float* __restrict__ src_c, const float* __restrict__ src_o,
    u16* __restrict__ dst_c, u16* __restrict__ dst_o, int K, int N) {
  const float* src = blockIdx.z ? src_o : src_c;
  u16* dst = blockIdx.z ? dst_o : dst_c;
  const int n0 = blockIdx.x * 64, k0 = blockIdx.y * 64;
  __shared__ float s[64][65];
  const int tid = threadIdx.x;
  const int r = tid >> 4, c4 = (tid & 15) << 2;
#pragma unroll
  for (int p = 0; p < 4; ++p) {
    int kk = r + p * 16;
    float4 v = *(const float4*)(src + (size_t)(k0 + kk) * N + n0 + c4);
    s[kk][c4] = v.x; s[kk][c4 + 1] = v.y; s[kk][c4 + 2] = v.z; s[kk][c4 + 3] = v.w;
  }
  __syncthreads();
#pragma unroll
  for (int p = 0; p < 4; ++p) {
    int nr = r + p * 16;
    ushort4 ov;
    ov.x = f2bf(s[c4 + 0][nr]); ov.y = f2bf(s[c4 + 1][nr]);
    ov.z = f2bf(s[c4 + 2][nr]); ov.w = f2bf(s[c4 + 3][nr]);
    *(ushort4*)(dst + (size_t)(n0 + nr) * K + k0 + c4) = ov;
  }
}

// ---------------- GEMM m97-style: A bf16 [M][K] x BT bf16 [N][K], 128xBNx32 ----------------
template <int BN>
__global__ __launch_bounds__(256) void gemm_bf16(
    const u16* __restrict__ A, const u16* __restrict__ BTc, const u16* __restrict__ BTo,
    int N, int K, int mode,
    const float* __restrict__ bias_c, const float* __restrict__ bias_o,
    const float* __restrict__ gate_c, const float* __restrict__ gate_o,
    const float* __restrict__ x0_c, const float* __restrict__ x0_o,
    const u16* __restrict__ x1, void* __restrict__ outp,
    u16* __restrict__ oq, u16* __restrict__ ok, u16* __restrict__ ov) {
  constexpr int MI = (BN == 128) ? 4 : 2;
  __shared__ u16 As[128 * 32];   // unpadded: global_load_lds is lane-linear
  __shared__ u16 Bs[BN * 32];
  const int tid = threadIdx.x;
  const int m0 = blockIdx.y * 128, n0 = blockIdx.x * BN;
  const bool is_c = (m0 < 1024);
  const u16* __restrict__ BT = is_c ? BTc : BTo;
  const int w = tid >> 6, lane = tid & 63, quad = lane >> 4, ln = lane & 15;
  const int wm = (BN == 128) ? (w >> 1) * 64 : w * 32;
  const int wn = (BN == 128) ? (w & 1) * 64 : 0;
  f32x4 acc[MI][4] = {};
  const int nkt = K >> 5;
  for (int kt = 0; kt < nkt; ++kt) {
    __syncthreads();
    {
      int c = tid;
      GLOAD_LDS16(A + (size_t)(m0 + (c >> 2)) * K + kt * 32 + (c & 3) * 8, As + c * 8);
      c = tid + 256;
      GLOAD_LDS16(A + (size_t)(m0 + (c >> 2)) * K + kt * 32 + (c & 3) * 8, As + c * 8);
      c = tid;
      GLOAD_LDS16(BT + (size_t)(n0 + (c >> 2)) * K + kt * 32 + (c & 3) * 8, Bs + c * 8);
      if (BN == 128) {
        c = tid + 256;
        GLOAD_LDS16(BT + (size_t)(n0 + (c >> 2)) * K + kt * 32 + (c & 3) * 8, Bs + c * 8);
      }
    }
    __syncthreads();
    bf16x8 a[MI], b[4];
#pragma unroll
    for (int i = 0; i < MI; ++i)
      a[i] = *(const bf16x8*)(As + (wm + i * 16 + ln) * 32 + quad * 8);
#pragma unroll
    for (int j = 0; j < 4; ++j)
      b[j] = *(const bf16x8*)(Bs + (wn + j * 16 + ln) * 32 + quad * 8);
#pragma unroll
    for (int i = 0; i < MI; ++i)
#pragma unroll
      for (int j = 0; j < 4; ++j) acc[i][j] = mfma16(a[i], b[j], acc[i][j]);
  }
  const float* bias = is_c ? bias_c : bias_o;
  const float* gate = is_c ? gate_c : gate_o;
  const float* x0 = is_c ? x0_c : x0_o;
#pragma unroll
  for (int i = 0; i < MI; ++i) {
#pragma unroll
    for (int j = 0; j < 4; ++j) {
#pragma unroll
      for (int r = 0; r < 4; ++r) {
        const int row = m0 + wm + i * 16 + quad * 4 + r;
        const int col = n0 + wn + j * 16 + ln;
        const float v = acc[i][j][r];
        if (mode == 0) {
          const int which = col >> 10, hh = (col & 1023) >> 6, dd = col & 63;
          u16* dst = (which == 0) ? oq : (which == 1) ? ok : ov;
          dst[((size_t)hh * 4096 + row) * 64 + dd] = f2bf(v);
        } else if (mode == 1) {
          const float xv = is_c ? x0[(size_t)row * 1024 + col]
                                : x0[(size_t)(row - 1024) * 1024 + col];
          ((u16*)outp)[(size_t)row * 1024 + col] = f2bf(xv + gate[col] * (v + bias[col]));
        } else if (mode == 2) {
          ((u16*)outp)[(size_t)row * N + col] = f2bf(gelu_tanh(v + bias[col]));
        } else {
          const float res = bf2f(x1[(size_t)row * 1024 + col]);
          const float val = res + gate[col] * (v + bias[col]);
          const size_t oidx = (row < 1024)
              ? (size_t)3145728 + (size_t)row * 1024 + col
              : (size_t)(row - 1024) * 1024 + col;
          ((float*)outp)[oidx] = val;
        }
      }
    }
  }
}

// ---- in-place rmsnorm+rope on head-major q,k; q pre-scaled by 0.125*log2(e) ----
__global__ __launch_bounds__(256) void qkprep_kernel(
    const float* __restrict__ pe,
    const float* __restrict__ qs_c, const float* __restrict__ ks_c,
    const float* __restrict__ qs_o, const float* __restrict__ ks_o,
    u16* __restrict__ qraw, u16* __restrict__ kraw) {
  const int l = blockIdx.x, tid = threadIdx.x;
  const bool is_c = l < 1024;
  const float* qs = is_c ? qs_c : qs_o;
  const float* ks = is_c ? ks_c : ks_o;
  const int head = tid >> 4, dd = (tid * 4) & 63;
  const size_t off = ((size_t)head * 4096 + l) * 64 + dd;
  const float* peb = pe + (size_t)l * 128 + (size_t)dd * 2;
  float4 pe0 = *(const float4*)(peb);
  float4 pe1 = *(const float4*)(peb + 4);
  {  // q (scaled into exp2-score domain)
    ushort4 raw = *(const ushort4*)(qraw + off);
    float x0 = bf2f(raw.x), x1v = bf2f(raw.y), x2 = bf2f(raw.z), x3 = bf2f(raw.w);
    float ssq = x0 * x0 + x1v * x1v + x2 * x2 + x3 * x3;
#pragma unroll
    for (int m = 1; m < 16; m <<= 1) ssq += __shfl_xor(ssq, m);
    float rms = rsqrtf(ssq * (1.0f / 64.0f) + 1e-6f) * 0.18033688011112042f;
    float n0 = x0 * rms * qs[dd + 0], n1 = x1v * rms * qs[dd + 1];
    float n2 = x2 * rms * qs[dd + 2], n3 = x3 * rms * qs[dd + 3];
    ushort4 o;
    o.x = f2bf(pe0.x * n0 + pe0.y * n1);
    o.y = f2bf(pe0.z * n0 + pe0.w * n1);
    o.z = f2bf(pe1.x * n2 + pe1.y * n3);
    o.w = f2bf(pe1.z * n2 + pe1.w * n3);
    *(ushort4*)(qraw + off) = o;
  }
  {  // k
    ushort4 raw = *(const ushort4*)(kraw + off);
    float x0 = bf2f(raw.x), x1v = bf2f(raw.y), x2 = bf2f(raw.z), x3 = bf2f(raw.w);
    float ssq = x0 * x0 + x1v * x1v + x2 * x2 + x3 * x3;
#pragma unroll
    for (int m = 1; m < 16; m <<= 1) ssq += __shfl_xor(ssq, m);
    float rms = rsqrtf(ssq * (1.0f / 64.0f) + 1e-6f);
    float n0 = x0 * rms * ks[dd + 0], n1 = x1v * rms * ks[dd + 1];
    float n2 = x2 * rms * ks[dd + 2], n3 = x3 * rms * ks[dd + 3];
    ushort4 o;
    o.x = f2bf(pe0.x * n0 + pe0.y * n1);
    o.y = f2bf(pe0.z * n0 + pe0.w * n1);
    o.z = f2bf(pe1.x * n2 + pe1.y * n3);
    o.w = f2bf(pe1.z * n2 + pe1.w * n3);
    *(ushort4*)(kraw + off) = o;
  }
}

// ---------------- one-shot V transpose: vraw[h][l][d] -> vt[h][d][l] ----------------
__global__ __launch_bounds__(256) void vtrans_kernel(
    const u16* __restrict__ vh, u16* __restrict__ vt) {
  const int h = blockIdx.y, k0 = blockIdx.x * 64;
  __shared__ u16 s[64 * 66];
  const int tid = threadIdx.x;
#pragma unroll
  for (int st = 0; st < 2; ++st) {
    int c = tid + st * 256;
    int row = c >> 3, off = (c & 7) << 3;
    ushort4 v0 = *(const ushort4*)(vh + ((size_t)h * 4096 + k0 + row) * 64 + off);
    ushort4 v1 = *(const ushort4*)(vh + ((size_t)h * 4096 + k0 + row) * 64 + off + 4);
    u16* p = s + row * 66 + off;
    p[0] = v0.x; p[1] = v0.y; p[2] = v0.z; p[3] = v0.w;
    p[4] = v1.x; p[5] = v1.y; p[6] = v1.z; p[7] = v1.w;
  }
  __syncthreads();
#pragma unroll
  for (int st = 0; st < 2; ++st) {
    int c = tid + st * 256;
    int dd = c >> 3, kk = (c & 7) << 3;
    ushort4 a, b;
    a.x = s[(kk + 0) * 66 + dd]; a.y = s[(kk + 1) * 66 + dd];
    a.z = s[(kk + 2) * 66 + dd]; a.w = s[(kk + 3) * 66 + dd];
    b.x = s[(kk + 4) * 66 + dd]; b.y = s[(kk + 5) * 66 + dd];
    b.z = s[(kk + 6) * 66 + dd]; b.w = s[(kk + 7) * 66 + dd];
    u16* o = vt + ((size_t)h * 64 + dd) * 4096 + k0 + kk;
    *(ushort4*)(o) = a;
    *(ushort4*)(o + 4) = b;
  }
}

// ---------------- flash attention v3: 128 q-rows/block, fixed-offset exp2 softmax ----------------
__global__ __launch_bounds__(256) void attn_kernel(
    const u16* __restrict__ qh, const u16* __restrict__ kh,
    const u16* __restrict__ vt, u16* __restrict__ attn) {
  constexpr int L = 4096;
  const int h = blockIdx.y;
  const int q0 = blockIdx.x * 128;
  const int tid = threadIdx.x, w = tid >> 6, lane = tid & 63;
  const int quad = lane >> 4, ln = lane & 15;
  const int wq = w * 32;
  __shared__ u16 QP[128 * 68];
  __shared__ u16 Ks[64 * 72];
  __shared__ u16 Vs[64 * 72];
  {
    const u16* qb = qh + ((size_t)h * L + q0) * 64;
#pragma unroll
    for (int st = 0; st < 4; ++st) {
      int c = tid + st * 256;
      int row = c >> 3, d0 = (c & 7) << 3;
      uint4 v = *(const uint4*)(qb + row * 64 + d0);
      *(uint2*)(QP + row * 68 + d0) = make_uint2(v.x, v.y);
      *(uint2*)(QP + row * 68 + d0 + 4) = make_uint2(v.z, v.w);
    }
  }
  __syncthreads();
  bf16x8 aq[2][2];
#pragma unroll
  for (int rg = 0; rg < 2; ++rg)
#pragma unroll
    for (int hf = 0; hf < 2; ++hf)
      aq[rg][hf] = ld8u(QP + (wq + rg * 16 + ln) * 68 + hf * 32 + quad * 8);

  f32x4 o[2][4] = {};
  f32x4 rs[2] = {};
  const u16* kbase = kh + (size_t)h * L * 64;
  const u16* vbase = vt + (size_t)h * 64 * L;
  for (int kt = 0; kt < 64; ++kt) {
    __syncthreads();
#pragma unroll
    for (int st = 0; st < 2; ++st) {
      int c = tid + st * 256;
      int row = c >> 3, off = (c & 7) << 3;
      *(uint4*)(Ks + row * 72 + off) =
          *(const uint4*)(kbase + (size_t)(kt * 64 + row) * 64 + off);
      *(uint4*)(Vs + row * 72 + off) =
          *(const uint4*)(vbase + (size_t)row * L + kt * 64 + off);
    }
    __syncthreads();
    f32x4 s[2][4] = {};
#pragma unroll
    for (int j = 0; j < 4; ++j) {
      bf16x8 b0 = *(const bf16x8*)(Ks + (j * 16 + ln) * 72 + quad * 8);
      bf16x8 b1 = *(const bf16x8*)(Ks + (j * 16 + ln) * 72 + 32 + quad * 8);
#pragma unroll
      for (int rg = 0; rg < 2; ++rg) {
        s[rg][j] = mfma16(aq[rg][0], b0, s[rg][j]);
        s[rg][j] = mfma16(aq[rg][1], b1, s[rg][j]);
      }
    }
#pragma unroll
    for (int rg = 0; rg < 2; ++rg)
#pragma unroll
      for (int j = 0; j < 4; ++j)
#pragma unroll
        for (int r = 0; r < 4; ++r) {
          float p = exp2f(s[rg][j][r] - 16.0f);   // scores pre-scaled; bounded => no max pass
          rs[rg][r] += p;
          QP[(wq + rg * 16 + quad * 4 + r) * 68 + j * 16 + ln] = f2bf_trunc(p);
        }
    bf16x8 ap[2][2];
#pragma unroll
    for (int rg = 0; rg < 2; ++rg)
#pragma unroll
      for (int hf = 0; hf < 2; ++hf)
        ap[rg][hf] = ld8u(QP + (wq + rg * 16 + ln) * 68 + hf * 32 + quad * 8);
#pragma unroll
    for (int jd = 0; jd < 4; ++jd) {
      bf16x8 v0 = *(const bf16x8*)(Vs + (jd * 16 + ln) * 72 + quad * 8);
      bf16x8 v1 = *(const bf16x8*)(Vs + (jd * 16 + ln) * 72 + 32 + quad * 8);
#pragma unroll
      for (int rg = 0; rg < 2; ++rg) {
        o[rg][jd] = mfma16(ap[rg][0], v0, o[rg][jd]);
        o[rg][jd] = mfma16(ap[rg][1], v1, o[rg][jd]);
      }
    }
  }
  float linv[2][4];
#pragma unroll
  for (int rg = 0; rg < 2; ++rg)
#pragma unroll
    for (int r = 0; r < 4; ++r) {
      float l = rs[rg][r];
#pragma unroll
      for (int m = 1; m < 16; m <<= 1) l += __shfl_xor(l, m);
      linv[rg][r] = 1.0f / l;
    }
#pragma unroll
  for (int rg = 0; rg < 2; ++rg)
#pragma unroll
    for (int jd = 0; jd < 4; ++jd)
#pragma unroll
      for (int r = 0; r < 4; ++r) {
        const int row = q0 + wq + rg * 16 + quad * 4 + r;
        attn[(size_t)row * 1024 + h * 64 + jd * 16 + ln] =
            f2bf(o[rg][jd][r] * linv[rg][r]);
      }
}

extern "C" void kernel_launch(void* const* d_in, const int* in_sizes, int n_in,
                              void* d_out, int out_size, void* d_ws, size_t ws_size,
                              hipStream_t stream) {
  (void)in_sizes; (void)n_in; (void)out_size; (void)ws_size;
  const float* obs         = (const float*)d_in[0];
  const float* cond        = (const float*)d_in[1];
  const float* vec         = (const float*)d_in[2];
  const float* pe          = (const float*)d_in[3];
  const float* obs_mod_w   = (const float*)d_in[4];
  const float* obs_mod_b   = (const float*)d_in[5];
  const float* obs_qkv_w   = (const float*)d_in[6];
  const float* obs_q_scale = (const float*)d_in[7];
  const float* obs_k_scale = (const float*)d_in[8];
  const float* obs_proj_w  = (const float*)d_in[9];
  const float* obs_proj_b  = (const float*)d_in[10];
  const float* obs_mlp_w1  = (const float*)d_in[11];
  const float* obs_mlp_b1  = (const float*)d_in[12];
  const float* obs_mlp_w2  = (const float*)d_in[13];
  const float* obs_mlp_b2  = (const float*)d_in[14];
  const float* cond_mod_w  = (const float*)d_in[15];
  const float* cond_mod_b  = (const float*)d_in[16];
  const float* cond_qkv_w  = (const float*)d_in[17];
  const float* cond_q_scale= (const float*)d_in[18];
  const float* cond_k_scale= (const float*)d_in[19];
  const float* cond_proj_w = (const float*)d_in[20];
  const float* cond_proj_b = (const float*)d_in[21];
  const float* cond_mlp_w1 = (const float*)d_in[22];
  const float* cond_mlp_b1 = (const float*)d_in[23];
  const float* cond_mlp_w2 = (const float*)d_in[24];
  const float* cond_mlp_b2 = (const float*)d_in[25];

  // Workspace (peak 64 MiB + 64 KiB — proven budget):
  //  [0,16M)   rotating bf16 weights: qkvT -> projT -> mlp1T -> mlp2T
  //  [16,24M)  xm -> x1(bf16)
  //  [24,32M)  qraw -> hm
  //  [32,40M)  kraw ─┐
  //  [40,48M)  vraw  ├─> g (32 MiB, spans 32..64M after all dead)
  //  [48,56M)  vt   ─┤
  //  [56,64M)  attn ─┘
  char* ws = (char*)d_ws;
  float* o_mod = (float*)ws;
  float* c_mod = o_mod + 6144;
  char* base = ws + 65536;
  u16* qkvT_c  = (u16*)base;
  u16* qkvT_o  = (u16*)(base + 6291456);
  u16* projT_c = (u16*)base;
  u16* projT_o = (u16*)(base + 2097152);
  u16* mlp1T_c = (u16*)base;
  u16* mlp1T_o = (u16*)(base + 8388608);
  u16* mlp2T_c = (u16*)base;
  u16* mlp2T_o = (u16*)(base + 8388608);
  u16* xm   = (u16*)(base + 16777216);
  u16* x1   = (u16*)(base + 16777216);
  u16* qraw = (u16*)(base + 25165824);
  u16* hm   = (u16*)(base + 25165824);
  u16* kraw = (u16*)(base + 33554432);
  u16* vraw = (u16*)(base + 41943040);
  u16* vt   = (u16*)(base + 50331648);
  u16* attn = (u16*)(base + 58720256);
  u16* g    = (u16*)(base + 33554432);

  modulation_kernel<<<192, 256, 0, stream>>>(vec, obs_mod_w, obs_mod_b,
                                             cond_mod_w, cond_mod_b, o_mod, c_mod);
  ln_mod_kernel<<<4096, 256, 0, stream>>>(cond, obs, c_mod, o_mod, 0, xm);
  transcast_kernel<<<dim3(48, 16, 2), 256, 0, stream>>>(cond_qkv_w, obs_qkv_w,
                                                        qkvT_c, qkvT_o, 1024, 3072);
  gemm_bf16<128><<<dim3(24, 32), 256, 0, stream>>>(xm, qkvT_c, qkvT_o, 3072, 1024, 0,
      nullptr, nullptr, nullptr, nullptr, nullptr, nullptr, nullptr, nullptr,
      qraw, kraw, vraw);
  qkprep_kernel<<<4096, 256, 0, stream>>>(pe, cond_q_scale, cond_k_scale,
                                          obs_q_scale, obs_k_scale, qraw, kraw);
  vtrans_kernel<<<dim3(64, 16), 256, 0, stream>>>(vraw, vt);
  attn_kernel<<<dim3(32, 16), 256, 0, stream>>>(qraw, kraw, vt, attn);
  transcast_kernel<<<dim3(16, 16, 2), 256, 0, stream>>>(cond_proj_w, obs_proj_w,
                                                        projT_c, projT_o, 1024, 1024);
  gemm_bf16<64><<<dim3(16, 32), 256, 0, stream>>>(attn, projT_c, projT_o, 1024, 1024, 1,
      cond_proj_b, obs_proj_b, c_mod + 2048, o_mod + 2048, cond, obs,
      nullptr, (void*)x1, nullptr, nullptr, nullptr);
  ln_mod_b_kernel<<<4096, 256, 0, stream>>>(x1, c_mod, o_mod, 3072, hm);
  transcast_kernel<<<dim3(64, 16, 2), 256, 0, stream>>>(cond_mlp_w1, obs_mlp_w1,
                                                        mlp1T_c, mlp1T_o, 1024, 4096);
  gemm_bf16<128><<<dim3(32, 32), 256, 0, stream>>>(hm, mlp1T_c, mlp1T_o, 4096, 1024, 2,
      cond_mlp_b1, obs_mlp_b1, nullptr, nullptr, nullptr, nullptr,
      nullptr, (void*)g, nullptr, nullptr, nullptr);
  transcast_kernel<<<dim3(16, 64, 2), 256, 0, stream>>>(cond_mlp_w2, obs_mlp_w2,
                                                        mlp2T_c, mlp2T_o, 4096, 1024);
  gemm_bf16<64><<<dim3(16, 32), 256, 0, stream>>>(g, mlp2T_c, mlp2T_o, 1024, 4096, 3,
      cond_mlp_b2, obs_mlp_b2, c_mod + 5120, o_mod + 5120, nullptr, nullptr,
      x1, d_out, nullptr, nullptr, nullptr);
}

// Round 5
// 668.803 us; speedup vs baseline: 1.8523x; 1.0154x over previous
//
#include <hip/hip_runtime.h>

typedef unsigned short u16;
typedef __bf16 bf16x8 __attribute__((ext_vector_type(8)));
typedef __bf16 bf16x4 __attribute__((ext_vector_type(4)));
typedef float f32x4 __attribute__((ext_vector_type(4)));

#define GLOAD_LDS16(g, l)                                                    \
  __builtin_amdgcn_global_load_lds(                                          \
      (const __attribute__((address_space(1))) void*)(g),                    \
      (__attribute__((address_space(3))) void*)(l), 16, 0, 0)

__device__ __forceinline__ u16 f2bf(float f) {
  unsigned int u = __float_as_uint(f);
  u += 0x7fffu + ((u >> 16) & 1u);   // RNE
  return (u16)(u >> 16);
}
__device__ __forceinline__ float bf2f(u16 h) {
  return __uint_as_float(((unsigned int)h) << 16);
}
// pack two f32 -> two bf16 (truncation) in one u32: low = a, high = b
__device__ __forceinline__ unsigned int pack_bf2(float a, float b) {
  return (__float_as_uint(b) & 0xffff0000u) | (__float_as_uint(a) >> 16);
}
__device__ __forceinline__ float gelu_tanh(float x) {
  float u = 0.7978845608028654f * (x + 0.044715f * x * x * x);
  float e = __expf(-2.0f * fabsf(u));
  float t = (1.0f - e) / (1.0f + e);
  t = (u >= 0.0f) ? t : -t;
  return 0.5f * x * (1.0f + t);
}
__device__ __forceinline__ f32x4 mfma16(bf16x8 a, bf16x8 b, f32x4 c) {
  return __builtin_amdgcn_mfma_f32_16x16x32_bf16(a, b, c, 0, 0, 0);
}
__device__ __forceinline__ bf16x8 ld8u(const u16* p) {  // 8B-aligned bf16x8
  bf16x4 a = *(const bf16x4*)p;
  bf16x4 b = *(const bf16x4*)(p + 4);
  return __builtin_shufflevector(a, b, 0, 1, 2, 3, 4, 5, 6, 7);
}

// ---------------- modulation: out = silu(vec) @ W + b ----------------
__global__ __launch_bounds__(256) void modulation_kernel(
    const float* __restrict__ vec,
    const float* __restrict__ w_o, const float* __restrict__ b_o,
    const float* __restrict__ w_c, const float* __restrict__ b_c,
    float* __restrict__ o_mod, float* __restrict__ c_mod) {
  __shared__ float sv[1024];
  __shared__ float red[256];
  const int tid = threadIdx.x;
  const bool isobs = blockIdx.x < 96;
  const float* w = isobs ? w_o : w_c;
  const float* b = isobs ? b_o : b_c;
  float* out = isobs ? o_mod : c_mod;
  const int jb = (isobs ? blockIdx.x : blockIdx.x - 96) * 64;
  const int col = tid & 63, sl = tid >> 6;
  for (int i = tid; i < 1024; i += 256) {
    float v = vec[i];
    sv[i] = v / (1.0f + __expf(-v));
  }
  __syncthreads();
  float acc = 0.0f;
  const int kb = sl * 256;
  for (int k = 0; k < 256; ++k)
    acc += sv[kb + k] * w[(size_t)(kb + k) * 6144 + jb + col];
  red[tid] = acc;
  __syncthreads();
  if (sl == 0)
    out[jb + col] = red[col] + red[col + 64] + red[col + 128] + red[col + 192] + b[jb + col];
}

// ------------- LayerNorm + (1+scale)*y + shift -> bf16 ; rows: cond first -------------
__global__ __launch_bounds__(256) void ln_mod_kernel(
    const float* __restrict__ xc, const float* __restrict__ xo,
    const float* __restrict__ modc, const float* __restrict__ modo,
    int mod_off, u16* __restrict__ out) {
  const int row = blockIdx.x, tid = threadIdx.x;
  const bool is_c = row < 1024;
  const float* x = is_c ? (xc + (size_t)row * 1024) : (xo + (size_t)(row - 1024) * 1024);
  const float* mod = (is_c ? modc : modo) + mod_off;
  float4 v = *(const float4*)(x + tid * 4);
  float s1 = v.x + v.y + v.z + v.w;
  float s2 = v.x * v.x + v.y * v.y + v.z * v.z + v.w * v.w;
#pragma unroll
  for (int m = 1; m < 64; m <<= 1) {
    s1 += __shfl_xor(s1, m);
    s2 += __shfl_xor(s2, m);
  }
  __shared__ float red[8];
  const int w = tid >> 6;
  if ((tid & 63) == 0) { red[w] = s1; red[4 + w] = s2; }
  __syncthreads();
  s1 = red[0] + red[1] + red[2] + red[3];
  s2 = red[4] + red[5] + red[6] + red[7];
  const float mean = s1 * (1.0f / 1024.0f);
  const float var = s2 * (1.0f / 1024.0f) - mean * mean;
  const float rstd = rsqrtf(var + 1e-6f);
  const int d = tid * 4;
  float vv[4] = {v.x, v.y, v.z, v.w};
  ushort4 ov;
  u16* po = (u16*)&ov;
#pragma unroll
  for (int i = 0; i < 4; ++i) {
    float y = (vv[i] - mean) * rstd;
    po[i] = f2bf((1.0f + mod[1024 + d + i]) * y + mod[d + i]);
  }
  *(ushort4*)(out + (size_t)row * 1024 + d) = ov;
}

// ---- same, bf16 input (x1 residual stream) ----
__global__ __launch_bounds__(256) void ln_mod_b_kernel(
    const u16* __restrict__ x,
    const float* __restrict__ modc, const float* __restrict__ modo,
    int mod_off, u16* __restrict__ out) {
  const int row = blockIdx.x, tid = threadIdx.x;
  const bool is_c = row < 1024;
  const float* mod = (is_c ? modc : modo) + mod_off;
  ushort4 rv = *(const ushort4*)(x + (size_t)row * 1024 + tid * 4);
  float vv[4] = {bf2f(rv.x), bf2f(rv.y), bf2f(rv.z), bf2f(rv.w)};
  float s1 = vv[0] + vv[1] + vv[2] + vv[3];
  float s2 = vv[0] * vv[0] + vv[1] * vv[1] + vv[2] * vv[2] + vv[3] * vv[3];
#pragma unroll
  for (int m = 1; m < 64; m <<= 1) {
    s1 += __shfl_xor(s1, m);
    s2 += __shfl_xor(s2, m);
  }
  __shared__ float red[8];
  const int w = tid >> 6;
  if ((tid & 63) == 0) { red[w] = s1; red[4 + w] = s2; }
  __syncthreads();
  s1 = red[0] + red[1] + red[2] + red[3];
  s2 = red[4] + red[5] + red[6] + red[7];
  const float mean = s1 * (1.0f / 1024.0f);
  const float var = s2 * (1.0f / 1024.0f) - mean * mean;
  const float rstd = rsqrtf(var + 1e-6f);
  const int d = tid * 4;
  ushort4 ov;
  u16* po = (u16*)&ov;
#pragma unroll
  for (int i = 0; i < 4; ++i) {
    float y = (vv[i] - mean) * rstd;
    po[i] = f2bf((1.0f + mod[1024 + d + i]) * y + mod[d + i]);
  }
  *(ushort4*)(out + (size_t)row * 1024 + d) = ov;
}

// ---- weight pre-cast+transpose: src f32 [K][N] -> dst bf16 [N][K] ----
__global__ __launch_bounds__(256) void transcast_kernel(
    const float* __restrict__ src_c, const float* __restrict__ src_o,
    u16* __restrict__ dst_c, u16* __restrict__ dst_o, int K, int N) {
  const float* src = blockIdx.z ? src_o : src_c;
  u16* dst = blockIdx.z ? dst_o : dst_c;
  const int n0 = blockIdx.x * 64, k0 = blockIdx.y * 64;
  __shared__ float s[64][65];
  const int tid = threadIdx.x;
  const int r = tid >> 4, c4 = (tid & 15) << 2;
#pragma unroll
  for (int p = 0; p < 4; ++p) {
    int kk = r + p * 16;
    float4 v = *(const float4*)(src + (size_t)(k0 + kk) * N + n0 + c4);
    s[kk][c4] = v.x; s[kk][c4 + 1] = v.y; s[kk][c4 + 2] = v.z; s[kk][c4 + 3] = v.w;
  }
  __syncthreads();
#pragma unroll
  for (int p = 0; p < 4; ++p) {
    int nr = r + p * 16;
    ushort4 ov;
    ov.x = f2bf(s[c4 + 0][nr]); ov.y = f2bf(s[c4 + 1][nr]);
    ov.z = f2bf(s[c4 + 2][nr]); ov.w = f2bf(s[c4 + 3][nr]);
    *(ushort4*)(dst + (size_t)(n0 + nr) * K + k0 + c4) = ov;
  }
}

// ---------------- GEMM m97-style: A bf16 [M][K] x BT bf16 [N][K], 128xBNx32 ----------------
template <int BN>
__global__ __launch_bounds__(256) void gemm_bf16(
    const u16* __restrict__ A, const u16* __restrict__ BTc, const u16* __restrict__ BTo,
    int N, int K, int mode,
    const float* __restrict__ bias_c, const float* __restrict__ bias_o,
    const float* __restrict__ gate_c, const float* __restrict__ gate_o,
    const float* __restrict__ x0_c, const float* __restrict__ x0_o,
    const u16* __restrict__ x1, void* __restrict__ outp,
    u16* __restrict__ oq, u16* __restrict__ ok, u16* __restrict__ ov) {
  constexpr int MI = (BN == 128) ? 4 : 2;
  __shared__ u16 As[128 * 32];   // unpadded: global_load_lds is lane-linear
  __shared__ u16 Bs[BN * 32];
  const int tid = threadIdx.x;
  const int m0 = blockIdx.y * 128, n0 = blockIdx.x * BN;
  const bool is_c = (m0 < 1024);
  const u16* __restrict__ BT = is_c ? BTc : BTo;
  const int w = tid >> 6, lane = tid & 63, quad = lane >> 4, ln = lane & 15;
  const int wm = (BN == 128) ? (w >> 1) * 64 : w * 32;
  const int wn = (BN == 128) ? (w & 1) * 64 : 0;
  f32x4 acc[MI][4] = {};
  const int nkt = K >> 5;
  for (int kt = 0; kt < nkt; ++kt) {
    __syncthreads();
    {
      int c = tid;
      GLOAD_LDS16(A + (size_t)(m0 + (c >> 2)) * K + kt * 32 + (c & 3) * 8, As + c * 8);
      c = tid + 256;
      GLOAD_LDS16(A + (size_t)(m0 + (c >> 2)) * K + kt * 32 + (c & 3) * 8, As + c * 8);
      c = tid;
      GLOAD_LDS16(BT + (size_t)(n0 + (c >> 2)) * K + kt * 32 + (c & 3) * 8, Bs + c * 8);
      if (BN == 128) {
        c = tid + 256;
        GLOAD_LDS16(BT + (size_t)(n0 + (c >> 2)) * K + kt * 32 + (c & 3) * 8, Bs + c * 8);
      }
    }
    __syncthreads();
    bf16x8 a[MI], b[4];
#pragma unroll
    for (int i = 0; i < MI; ++i)
      a[i] = *(const bf16x8*)(As + (wm + i * 16 + ln) * 32 + quad * 8);
#pragma unroll
    for (int j = 0; j < 4; ++j)
      b[j] = *(const bf16x8*)(Bs + (wn + j * 16 + ln) * 32 + quad * 8);
#pragma unroll
    for (int i = 0; i < MI; ++i)
#pragma unroll
      for (int j = 0; j < 4; ++j) acc[i][j] = mfma16(a[i], b[j], acc[i][j]);
  }
  const float* bias = is_c ? bias_c : bias_o;
  const float* gate = is_c ? gate_c : gate_o;
  const float* x0 = is_c ? x0_c : x0_o;
#pragma unroll
  for (int i = 0; i < MI; ++i) {
#pragma unroll
    for (int j = 0; j < 4; ++j) {
#pragma unroll
      for (int r = 0; r < 4; ++r) {
        const int row = m0 + wm + i * 16 + quad * 4 + r;
        const int col = n0 + wn + j * 16 + ln;
        const float v = acc[i][j][r];
        if (mode == 0) {
          const int which = col >> 10, hh = (col & 1023) >> 6, dd = col & 63;
          u16* dst = (which == 0) ? oq : (which == 1) ? ok : ov;
          dst[((size_t)hh * 4096 + row) * 64 + dd] = f2bf(v);
        } else if (mode == 1) {
          const float xv = is_c ? x0[(size_t)row * 1024 + col]
                                : x0[(size_t)(row - 1024) * 1024 + col];
          ((u16*)outp)[(size_t)row * 1024 + col] = f2bf(xv + gate[col] * (v + bias[col]));
        } else if (mode == 2) {
          ((u16*)outp)[(size_t)row * N + col] = f2bf(gelu_tanh(v + bias[col]));
        } else {
          const float res = bf2f(x1[(size_t)row * 1024 + col]);
          const float val = res + gate[col] * (v + bias[col]);
          const size_t oidx = (row < 1024)
              ? (size_t)3145728 + (size_t)row * 1024 + col
              : (size_t)(row - 1024) * 1024 + col;
          ((float*)outp)[oidx] = val;
        }
      }
    }
  }
}

// ---- in-place rmsnorm+rope on head-major q,k; q pre-scaled by 0.125*log2(e) ----
__global__ __launch_bounds__(256) void qkprep_kernel(
    const float* __restrict__ pe,
    const float* __restrict__ qs_c, const float* __restrict__ ks_c,
    const float* __restrict__ qs_o, const float* __restrict__ ks_o,
    u16* __restrict__ qraw, u16* __restrict__ kraw) {
  const int l = blockIdx.x, tid = threadIdx.x;
  const bool is_c = l < 1024;
  const float* qs = is_c ? qs_c : qs_o;
  const float* ks = is_c ? ks_c : ks_o;
  const int head = tid >> 4, dd = (tid * 4) & 63;
  const size_t off = ((size_t)head * 4096 + l) * 64 + dd;
  const float* peb = pe + (size_t)l * 128 + (size_t)dd * 2;
  float4 pe0 = *(const float4*)(peb);
  float4 pe1 = *(const float4*)(peb + 4);
  {  // q (scaled into exp2-score domain)
    ushort4 raw = *(const ushort4*)(qraw + off);
    float x0 = bf2f(raw.x), x1v = bf2f(raw.y), x2 = bf2f(raw.z), x3 = bf2f(raw.w);
    float ssq = x0 * x0 + x1v * x1v + x2 * x2 + x3 * x3;
#pragma unroll
    for (int m = 1; m < 16; m <<= 1) ssq += __shfl_xor(ssq, m);
    float rms = rsqrtf(ssq * (1.0f / 64.0f) + 1e-6f) * 0.18033688011112042f;
    float n0 = x0 * rms * qs[dd + 0], n1 = x1v * rms * qs[dd + 1];
    float n2 = x2 * rms * qs[dd + 2], n3 = x3 * rms * qs[dd + 3];
    ushort4 o;
    o.x = f2bf(pe0.x * n0 + pe0.y * n1);
    o.y = f2bf(pe0.z * n0 + pe0.w * n1);
    o.z = f2bf(pe1.x * n2 + pe1.y * n3);
    o.w = f2bf(pe1.z * n2 + pe1.w * n3);
    *(ushort4*)(qraw + off) = o;
  }
  {  // k
    ushort4 raw = *(const ushort4*)(kraw + off);
    float x0 = bf2f(raw.x), x1v = bf2f(raw.y), x2 = bf2f(raw.z), x3 = bf2f(raw.w);
    float ssq = x0 * x0 + x1v * x1v + x2 * x2 + x3 * x3;
#pragma unroll
    for (int m = 1; m < 16; m <<= 1) ssq += __shfl_xor(ssq, m);
    float rms = rsqrtf(ssq * (1.0f / 64.0f) + 1e-6f);
    float n0 = x0 * rms * ks[dd + 0], n1 = x1v * rms * ks[dd + 1];
    float n2 = x2 * rms * ks[dd + 2], n3 = x3 * rms * ks[dd + 3];
    ushort4 o;
    o.x = f2bf(pe0.x * n0 + pe0.y * n1);
    o.y = f2bf(pe0.z * n0 + pe0.w * n1);
    o.z = f2bf(pe1.x * n2 + pe1.y * n3);
    o.w = f2bf(pe1.z * n2 + pe1.w * n3);
    *(ushort4*)(kraw + off) = o;
  }
}

// ---------------- one-shot V transpose: vraw[h][l][d] -> vt[h][d][l] ----------------
__global__ __launch_bounds__(256) void vtrans_kernel(
    const u16* __restrict__ vh, u16* __restrict__ vt) {
  const int h = blockIdx.y, k0 = blockIdx.x * 64;
  __shared__ u16 s[64 * 66];
  const int tid = threadIdx.x;
#pragma unroll
  for (int st = 0; st < 2; ++st) {
    int c = tid + st * 256;
    int row = c >> 3, off = (c & 7) << 3;
    ushort4 v0 = *(const ushort4*)(vh + ((size_t)h * 4096 + k0 + row) * 64 + off);
    ushort4 v1 = *(const ushort4*)(vh + ((size_t)h * 4096 + k0 + row) * 64 + off + 4);
    u16* p = s + row * 66 + off;
    p[0] = v0.x; p[1] = v0.y; p[2] = v0.z; p[3] = v0.w;
    p[4] = v1.x; p[5] = v1.y; p[6] = v1.z; p[7] = v1.w;
  }
  __syncthreads();
#pragma unroll
  for (int st = 0; st < 2; ++st) {
    int c = tid + st * 256;
    int dd = c >> 3, kk = (c & 7) << 3;
    ushort4 a, b;
    a.x = s[(kk + 0) * 66 + dd]; a.y = s[(kk + 1) * 66 + dd];
    a.z = s[(kk + 2) * 66 + dd]; a.w = s[(kk + 3) * 66 + dd];
    b.x = s[(kk + 4) * 66 + dd]; b.y = s[(kk + 5) * 66 + dd];
    b.z = s[(kk + 6) * 66 + dd]; b.w = s[(kk + 7) * 66 + dd];
    u16* o = vt + ((size_t)h * 64 + dd) * 4096 + k0 + kk;
    *(ushort4*)(o) = a;
    *(ushort4*)(o + 4) = b;
  }
}

// ---------------- flash attention v4: wave-partitioned keys, S^T trick ----------------
// Each wave owns keys {c*128 + w*32 .. +32} — K/Q/V frags load DIRECTLY from global
// (no LDS staging, no barriers in k-loop). S^T = mfma(a=K,b=Q) puts keys in the
// C-frag row index, so P[qrow][key] writes are r-consecutive b64 and A-frag reads
// are b64 — 16 LDS instrs per wave-chunk vs ~90 in v3. Cross-wave o/l reduced once
// at the end via a pairwise LDS tree (buffers overlay the dead P region).
__global__ __launch_bounds__(256) void attn_kernel(
    const u16* __restrict__ qh, const u16* __restrict__ kh,
    const u16* __restrict__ vt, u16* __restrict__ attn) {
  constexpr int L = 4096;
  const int h = blockIdx.y;
  const int q0 = blockIdx.x * 64;
  const int tid = threadIdx.x, w = tid >> 6, lane = tid & 63;
  const int quad = lane >> 4, ln = lane & 15;
  // LDS map: [0,18432) per-wave P[64][36] u16 (wave w at w*4608 B)
  // epilogue overlay: bufA f32[64][68] @0, bufB @17408, rs4[4][64] @34816
  __shared__ __align__(16) char smem[35840];
  u16* Pw = (u16*)(smem) + (size_t)w * 2304;
  float* bufA = (float*)smem;
  float* bufB = bufA + 4352;
  float* rs4 = bufB + 4352;

  // Q-frags (B-operand), loaded once from global
  bf16x8 bq[4][2];
  const u16* qbase = qh + ((size_t)h * L + q0) * 64;
#pragma unroll
  for (int nq = 0; nq < 4; ++nq)
#pragma unroll
    for (int hf = 0; hf < 2; ++hf)
      bq[nq][hf] = *(const bf16x8*)(qbase + (nq * 16 + ln) * 64 + hf * 32 + quad * 8);

  f32x4 o[4][4] = {};
  float rs[4] = {0.f, 0.f, 0.f, 0.f};
  const u16* kbase = kh + (size_t)h * L * 64;
  const u16* vbase = vt + (size_t)h * 64 * L;

  for (int c = 0; c < 32; ++c) {
    const int kb = c * 128 + w * 32;   // this wave's 32 keys
    // K-frags (A-operand) direct from global
    bf16x8 ak[2][2];
#pragma unroll
    for (int kk = 0; kk < 2; ++kk)
#pragma unroll
      for (int hf = 0; hf < 2; ++hf)
        ak[kk][hf] = *(const bf16x8*)(kbase + (size_t)(kb + kk * 16 + ln) * 64 + hf * 32 + quad * 8);
    // S^T[key][qrow]
    f32x4 sT[2][4] = {};
#pragma unroll
    for (int kk = 0; kk < 2; ++kk)
#pragma unroll
      for (int nq = 0; nq < 4; ++nq) {
        sT[kk][nq] = mfma16(ak[kk][0], bq[nq][0], sT[kk][nq]);
        sT[kk][nq] = mfma16(ak[kk][1], bq[nq][1], sT[kk][nq]);
      }
    // exp2 (scores pre-scaled by 0.125*log2e; bounded => no max pass, no offset),
    // accumulate row-sums, pack pairs, b64 store into wave-private P[qrow][key]
#pragma unroll
    for (int kk = 0; kk < 2; ++kk)
#pragma unroll
      for (int nq = 0; nq < 4; ++nq) {
        float p0 = exp2f(sT[kk][nq][0]);
        float p1 = exp2f(sT[kk][nq][1]);
        float p2 = exp2f(sT[kk][nq][2]);
        float p3 = exp2f(sT[kk][nq][3]);
        rs[nq] += (p0 + p1) + (p2 + p3);
        uint2 pk;
        pk.x = pack_bf2(p0, p1);
        pk.y = pack_bf2(p2, p3);
        *(uint2*)(Pw + (nq * 16 + ln) * 36 + kk * 16 + quad * 4) = pk;
      }
    // P A-frags (b64 pairs, wave-private => same-wave DS ordering, no barrier)
    bf16x8 ap[4];
#pragma unroll
    for (int nq = 0; nq < 4; ++nq)
      ap[nq] = ld8u(Pw + (nq * 16 + ln) * 36 + quad * 8);
    // V-frags (B-operand) direct from global vt[h][dim][key]
#pragma unroll
    for (int jd = 0; jd < 4; ++jd) {
      bf16x8 bv = *(const bf16x8*)(vbase + (size_t)(jd * 16 + ln) * L + kb + quad * 8);
#pragma unroll
      for (int nq = 0; nq < 4; ++nq)
        o[nq][jd] = mfma16(ap[nq], bv, o[nq][jd]);
    }
  }

  // ---- epilogue: cross-wave reduction of o and rs ----
  __syncthreads();   // all waves done with P region (bufs overlay it)
#pragma unroll
  for (int nq = 0; nq < 4; ++nq) {   // sum rs over the 4 quads (disjoint keys)
    rs[nq] += __shfl_xor(rs[nq], 16);
    rs[nq] += __shfl_xor(rs[nq], 32);
  }
  if (quad == 0) {
#pragma unroll
    for (int nq = 0; nq < 4; ++nq) rs4[w * 64 + nq * 16 + ln] = rs[nq];
  }
  if (w == 1) {
#pragma unroll
    for (int nq = 0; nq < 4; ++nq)
#pragma unroll
      for (int jd = 0; jd < 4; ++jd)
        *(f32x4*)(bufA + (jd * 16 + ln) * 68 + nq * 16 + quad * 4) = o[nq][jd];
  }
  if (w == 3) {
#pragma unroll
    for (int nq = 0; nq < 4; ++nq)
#pragma unroll
      for (int jd = 0; jd < 4; ++jd)
        *(f32x4*)(bufB + (jd * 16 + ln) * 68 + nq * 16 + quad * 4) = o[nq][jd];
  }
  __syncthreads();
  if (w == 0) {
#pragma unroll
    for (int nq = 0; nq < 4; ++nq)
#pragma unroll
      for (int jd = 0; jd < 4; ++jd)
        o[nq][jd] += *(const f32x4*)(bufA + (jd * 16 + ln) * 68 + nq * 16 + quad * 4);
  }
  if (w == 2) {
#pragma unroll
    for (int nq = 0; nq < 4; ++nq)
#pragma unroll
      for (int jd = 0; jd < 4; ++jd)
        o[nq][jd] += *(const f32x4*)(bufB + (jd * 16 + ln) * 68 + nq * 16 + quad * 4);
  }
  __syncthreads();
  if (w == 2) {
#pragma unroll
    for (int nq = 0; nq < 4; ++nq)
#pragma unroll
      for (int jd = 0; jd < 4; ++jd)
        *(f32x4*)(bufA + (jd * 16 + ln) * 68 + nq * 16 + quad * 4) = o[nq][jd];
  }
  __syncthreads();
  if (w == 0) {
    float linv[4][4];
#pragma unroll
    for (int nq = 0; nq < 4; ++nq)
#pragma unroll
      for (int r = 0; r < 4; ++r) {
        const int qr = nq * 16 + quad * 4 + r;
        linv[nq][r] = 1.0f / (rs4[qr] + rs4[64 + qr] + rs4[128 + qr] + rs4[192 + qr]);
      }
#pragma unroll
    for (int nq = 0; nq < 4; ++nq)
#pragma unroll
      for (int jd = 0; jd < 4; ++jd) {
        f32x4 of = o[nq][jd];
        of += *(const f32x4*)(bufA + (jd * 16 + ln) * 68 + nq * 16 + quad * 4);
#pragma unroll
        for (int r = 0; r < 4; ++r) {
          const int row = q0 + nq * 16 + quad * 4 + r;
          attn[(size_t)row * 1024 + h * 64 + jd * 16 + ln] = f2bf(of[r] * linv[nq][r]);
        }
      }
  }
}

extern "C" void kernel_launch(void* const* d_in, const int* in_sizes, int n_in,
                              void* d_out, int out_size, void* d_ws, size_t ws_size,
                              hipStream_t stream) {
  (void)in_sizes; (void)n_in; (void)out_size; (void)ws_size;
  const float* obs         = (const float*)d_in[0];
  const float* cond        = (const float*)d_in[1];
  const float* vec         = (const float*)d_in[2];
  const float* pe          = (const float*)d_in[3];
  const float* obs_mod_w   = (const float*)d_in[4];
  const float* obs_mod_b   = (const float*)d_in[5];
  const float* obs_qkv_w   = (const float*)d_in[6];
  const float* obs_q_scale = (const float*)d_in[7];
  const float* obs_k_scale = (const float*)d_in[8];
  const float* obs_proj_w  = (const float*)d_in[9];
  const float* obs_proj_b  = (const float*)d_in[10];
  const float* obs_mlp_w1  = (const float*)d_in[11];
  const float* obs_mlp_b1  = (const float*)d_in[12];
  const float* obs_mlp_w2  = (const float*)d_in[13];
  const float* obs_mlp_b2  = (const float*)d_in[14];
  const float* cond_mod_w  = (const float*)d_in[15];
  const float* cond_mod_b  = (const float*)d_in[16];
  const float* cond_qkv_w  = (const float*)d_in[17];
  const float* cond_q_scale= (const float*)d_in[18];
  const float* cond_k_scale= (const float*)d_in[19];
  const float* cond_proj_w = (const float*)d_in[20];
  const float* cond_proj_b = (const float*)d_in[21];
  const float* cond_mlp_w1 = (const float*)d_in[22];
  const float* cond_mlp_b1 = (const float*)d_in[23];
  const float* cond_mlp_w2 = (const float*)d_in[24];
  const float* cond_mlp_b2 = (const float*)d_in[25];

  // Workspace (peak 64 MiB + 64 KiB — proven budget):
  //  [0,16M)   rotating bf16 weights: qkvT -> projT -> mlp1T -> mlp2T
  //  [16,24M)  xm -> x1(bf16)
  //  [24,32M)  qraw -> hm
  //  [32,40M)  kraw ─┐
  //  [40,48M)  vraw  ├─> g (32 MiB, spans 32..64M after all dead)
  //  [48,56M)  vt   ─┤
  //  [56,64M)  attn ─┘
  char* ws = (char*)d_ws;
  float* o_mod = (float*)ws;
  float* c_mod = o_mod + 6144;
  char* base = ws + 65536;
  u16* qkvT_c  = (u16*)base;
  u16* qkvT_o  = (u16*)(base + 6291456);
  u16* projT_c = (u16*)base;
  u16* projT_o = (u16*)(base + 2097152);
  u16* mlp1T_c = (u16*)base;
  u16* mlp1T_o = (u16*)(base + 8388608);
  u16* mlp2T_c = (u16*)base;
  u16* mlp2T_o = (u16*)(base + 8388608);
  u16* xm   = (u16*)(base + 16777216);
  u16* x1   = (u16*)(base + 16777216);
  u16* qraw = (u16*)(base + 25165824);
  u16* hm   = (u16*)(base + 25165824);
  u16* kraw = (u16*)(base + 33554432);
  u16* vraw = (u16*)(base + 41943040);
  u16* vt   = (u16*)(base + 50331648);
  u16* attn = (u16*)(base + 58720256);
  u16* g    = (u16*)(base + 33554432);

  modulation_kernel<<<192, 256, 0, stream>>>(vec, obs_mod_w, obs_mod_b,
                                             cond_mod_w, cond_mod_b, o_mod, c_mod);
  ln_mod_kernel<<<4096, 256, 0, stream>>>(cond, obs, c_mod, o_mod, 0, xm);
  transcast_kernel<<<dim3(48, 16, 2), 256, 0, stream>>>(cond_qkv_w, obs_qkv_w,
                                                        qkvT_c, qkvT_o, 1024, 3072);
  gemm_bf16<128><<<dim3(24, 32), 256, 0, stream>>>(xm, qkvT_c, qkvT_o, 3072, 1024, 0,
      nullptr, nullptr, nullptr, nullptr, nullptr, nullptr, nullptr, nullptr,
      qraw, kraw, vraw);
  qkprep_kernel<<<4096, 256, 0, stream>>>(pe, cond_q_scale, cond_k_scale,
                                          obs_q_scale, obs_k_scale, qraw, kraw);
  vtrans_kernel<<<dim3(64, 16), 256, 0, stream>>>(vraw, vt);
  attn_kernel<<<dim3(64, 16), 256, 0, stream>>>(qraw, kraw, vt, attn);
  transcast_kernel<<<dim3(16, 16, 2), 256, 0, stream>>>(cond_proj_w, obs_proj_w,
                                                        projT_c, projT_o, 1024, 1024);
  gemm_bf16<64><<<dim3(16, 32), 256, 0, stream>>>(attn, projT_c, projT_o, 1024, 1024, 1,
      cond_proj_b, obs_proj_b, c_mod + 2048, o_mod + 2048, cond, obs,
      nullptr, (void*)x1, nullptr, nullptr, nullptr);
  ln_mod_b_kernel<<<4096, 256, 0, stream>>>(x1, c_mod, o_mod, 3072, hm);
  transcast_kernel<<<dim3(64, 16, 2), 256, 0, stream>>>(cond_mlp_w1, obs_mlp_w1,
                                                        mlp1T_c, mlp1T_o, 1024, 4096);
  gemm_bf16<128><<<dim3(32, 32), 256, 0, stream>>>(hm, mlp1T_c, mlp1T_o, 4096, 1024, 2,
      cond_mlp_b1, obs_mlp_b1, nullptr, nullptr, nullptr, nullptr,
      nullptr, (void*)g, nullptr, nullptr, nullptr);
  transcast_kernel<<<dim3(16, 64, 2), 256, 0, stream>>>(cond_mlp_w2, obs_mlp_w2,
                                                        mlp2T_c, mlp2T_o, 4096, 1024);
  gemm_bf16<64><<<dim3(16, 32), 256, 0, stream>>>(g, mlp2T_c, mlp2T_o, 1024, 4096, 3,
      cond_mlp_b2, obs_mlp_b2, c_mod + 5120, o_mod + 5120, nullptr, nullptr,
      x1, d_out, nullptr, nullptr, nullptr);
}

// Round 6
// 647.864 us; speedup vs baseline: 1.9121x; 1.0323x over previous
//
#include <hip/hip_runtime.h>

typedef unsigned short u16;
typedef __bf16 bf16x8 __attribute__((ext_vector_type(8)));
typedef __bf16 bf16x4 __attribute__((ext_vector_type(4)));
typedef float f32x4 __attribute__((ext_vector_type(4)));

#define GLOAD_LDS16(g, l)                                                    \
  __builtin_amdgcn_global_load_lds(                                          \
      (const __attribute__((address_space(1))) void*)(g),                    \
      (__attribute__((address_space(3))) void*)(l), 16, 0, 0)

__device__ __forceinline__ u16 f2bf(float f) {
  unsigned int u = __float_as_uint(f);
  u += 0x7fffu + ((u >> 16) & 1u);   // RNE
  return (u16)(u >> 16);
}
__device__ __forceinline__ float bf2f(u16 h) {
  return __uint_as_float(((unsigned int)h) << 16);
}
// pack two f32 -> two bf16 (truncation) in one u32: low = a, high = b
__device__ __forceinline__ unsigned int pack_bf2(float a, float b) {
  return (__float_as_uint(b) & 0xffff0000u) | (__float_as_uint(a) >> 16);
}
// raw v_exp_f32 — skips OCML denorm fixup. Safe: all inputs bounded (see call sites).
__device__ __forceinline__ float fexp2(float x) {
#if __has_builtin(__builtin_amdgcn_exp2f)
  return __builtin_amdgcn_exp2f(x);
#else
  return exp2f(x);
#endif
}
__device__ __forceinline__ float gelu_tanh(float x) {
  float u = 0.7978845608028654f * (x + 0.044715f * x * x * x);
  // exp(-2|u|) = 2^(-2*log2e*|u|); |u| bounded by gemm outputs -> no denorm concern
  float e = fexp2(-2.8853900817779268f * fabsf(u));
  float t = (1.0f - e) / (1.0f + e);
  t = (u >= 0.0f) ? t : -t;
  return 0.5f * x * (1.0f + t);
}
__device__ __forceinline__ float silu_f(float v) {
  return v / (1.0f + fexp2(-1.4426950408889634f * v));
}
__device__ __forceinline__ f32x4 mfma16(bf16x8 a, bf16x8 b, f32x4 c) {
  return __builtin_amdgcn_mfma_f32_16x16x32_bf16(a, b, c, 0, 0, 0);
}
__device__ __forceinline__ bf16x8 ld8u(const u16* p) {  // 8B-aligned bf16x8
  bf16x4 a = *(const bf16x4*)p;
  bf16x4 b = *(const bf16x4*)(p + 4);
  return __builtin_shufflevector(a, b, 0, 1, 2, 3, 4, 5, 6, 7);
}

// ---------------- modulation: out = silu(vec) @ W + b ----------------
__global__ __launch_bounds__(256) void modulation_kernel(
    const float* __restrict__ vec,
    const float* __restrict__ w_o, const float* __restrict__ b_o,
    const float* __restrict__ w_c, const float* __restrict__ b_c,
    float* __restrict__ o_mod, float* __restrict__ c_mod) {
  __shared__ float sv[1024];
  __shared__ float red[256];
  const int tid = threadIdx.x;
  const bool isobs = blockIdx.x < 96;
  const float* w = isobs ? w_o : w_c;
  const float* b = isobs ? b_o : b_c;
  float* out = isobs ? o_mod : c_mod;
  const int jb = (isobs ? blockIdx.x : blockIdx.x - 96) * 64;
  const int col = tid & 63, sl = tid >> 6;
  for (int i = tid; i < 1024; i += 256) {
    sv[i] = silu_f(vec[i]);
  }
  __syncthreads();
  float acc = 0.0f;
  const int kb = sl * 256;
  for (int k = 0; k < 256; ++k)
    acc += sv[kb + k] * w[(size_t)(kb + k) * 6144 + jb + col];
  red[tid] = acc;
  __syncthreads();
  if (sl == 0)
    out[jb + col] = red[col] + red[col + 64] + red[col + 128] + red[col + 192] + b[jb + col];
}

// ------------- LayerNorm + (1+scale)*y + shift -> bf16 ; rows: cond first -------------
__global__ __launch_bounds__(256) void ln_mod_kernel(
    const float* __restrict__ xc, const float* __restrict__ xo,
    const float* __restrict__ modc, const float* __restrict__ modo,
    int mod_off, u16* __restrict__ out) {
  const int row = blockIdx.x, tid = threadIdx.x;
  const bool is_c = row < 1024;
  const float* x = is_c ? (xc + (size_t)row * 1024) : (xo + (size_t)(row - 1024) * 1024);
  const float* mod = (is_c ? modc : modo) + mod_off;
  float4 v = *(const float4*)(x + tid * 4);
  float s1 = v.x + v.y + v.z + v.w;
  float s2 = v.x * v.x + v.y * v.y + v.z * v.z + v.w * v.w;
#pragma unroll
  for (int m = 1; m < 64; m <<= 1) {
    s1 += __shfl_xor(s1, m);
    s2 += __shfl_xor(s2, m);
  }
  __shared__ float red[8];
  const int w = tid >> 6;
  if ((tid & 63) == 0) { red[w] = s1; red[4 + w] = s2; }
  __syncthreads();
  s1 = red[0] + red[1] + red[2] + red[3];
  s2 = red[4] + red[5] + red[6] + red[7];
  const float mean = s1 * (1.0f / 1024.0f);
  const float var = s2 * (1.0f / 1024.0f) - mean * mean;
  const float rstd = rsqrtf(var + 1e-6f);
  const int d = tid * 4;
  float vv[4] = {v.x, v.y, v.z, v.w};
  ushort4 ov;
  u16* po = (u16*)&ov;
#pragma unroll
  for (int i = 0; i < 4; ++i) {
    float y = (vv[i] - mean) * rstd;
    po[i] = f2bf((1.0f + mod[1024 + d + i]) * y + mod[d + i]);
  }
  *(ushort4*)(out + (size_t)row * 1024 + d) = ov;
}

// ---- same, bf16 input (x1 residual stream) ----
__global__ __launch_bounds__(256) void ln_mod_b_kernel(
    const u16* __restrict__ x,
    const float* __restrict__ modc, const float* __restrict__ modo,
    int mod_off, u16* __restrict__ out) {
  const int row = blockIdx.x, tid = threadIdx.x;
  const bool is_c = row < 1024;
  const float* mod = (is_c ? modc : modo) + mod_off;
  ushort4 rv = *(const ushort4*)(x + (size_t)row * 1024 + tid * 4);
  float vv[4] = {bf2f(rv.x), bf2f(rv.y), bf2f(rv.z), bf2f(rv.w)};
  float s1 = vv[0] + vv[1] + vv[2] + vv[3];
  float s2 = vv[0] * vv[0] + vv[1] * vv[1] + vv[2] * vv[2] + vv[3] * vv[3];
#pragma unroll
  for (int m = 1; m < 64; m <<= 1) {
    s1 += __shfl_xor(s1, m);
    s2 += __shfl_xor(s2, m);
  }
  __shared__ float red[8];
  const int w = tid >> 6;
  if ((tid & 63) == 0) { red[w] = s1; red[4 + w] = s2; }
  __syncthreads();
  s1 = red[0] + red[1] + red[2] + red[3];
  s2 = red[4] + red[5] + red[6] + red[7];
  const float mean = s1 * (1.0f / 1024.0f);
  const float var = s2 * (1.0f / 1024.0f) - mean * mean;
  const float rstd = rsqrtf(var + 1e-6f);
  const int d = tid * 4;
  ushort4 ov;
  u16* po = (u16*)&ov;
#pragma unroll
  for (int i = 0; i < 4; ++i) {
    float y = (vv[i] - mean) * rstd;
    po[i] = f2bf((1.0f + mod[1024 + d + i]) * y + mod[d + i]);
  }
  *(ushort4*)(out + (size_t)row * 1024 + d) = ov;
}

// ---- weight pre-cast+transpose: src f32 [K][N] -> dst bf16 [N][K] ----
__global__ __launch_bounds__(256) void transcast_kernel(
    const float* __restrict__ src_c, const float* __restrict__ src_o,
    u16* __restrict__ dst_c, u16* __restrict__ dst_o, int K, int N) {
  const float* src = blockIdx.z ? src_o : src_c;
  u16* dst = blockIdx.z ? dst_o : dst_c;
  const int n0 = blockIdx.x * 64, k0 = blockIdx.y * 64;
  __shared__ float s[64][65];
  const int tid = threadIdx.x;
  const int r = tid >> 4, c4 = (tid & 15) << 2;
#pragma unroll
  for (int p = 0; p < 4; ++p) {
    int kk = r + p * 16;
    float4 v = *(const float4*)(src + (size_t)(k0 + kk) * N + n0 + c4);
    s[kk][c4] = v.x; s[kk][c4 + 1] = v.y; s[kk][c4 + 2] = v.z; s[kk][c4 + 3] = v.w;
  }
  __syncthreads();
#pragma unroll
  for (int p = 0; p < 4; ++p) {
    int nr = r + p * 16;
    ushort4 ov;
    ov.x = f2bf(s[c4 + 0][nr]); ov.y = f2bf(s[c4 + 1][nr]);
    ov.z = f2bf(s[c4 + 2][nr]); ov.w = f2bf(s[c4 + 3][nr]);
    *(ushort4*)(dst + (size_t)(n0 + nr) * K + k0 + c4) = ov;
  }
}

// ---------------- GEMM m97-style: A bf16 [M][K] x BT bf16 [N][K], 128xBNx32 ----------------
template <int BN>
__global__ __launch_bounds__(256) void gemm_bf16(
    const u16* __restrict__ A, const u16* __restrict__ BTc, const u16* __restrict__ BTo,
    int N, int K, int mode,
    const float* __restrict__ bias_c, const float* __restrict__ bias_o,
    const float* __restrict__ gate_c, const float* __restrict__ gate_o,
    const float* __restrict__ x0_c, const float* __restrict__ x0_o,
    const u16* __restrict__ x1, void* __restrict__ outp,
    u16* __restrict__ oq, u16* __restrict__ ok, u16* __restrict__ ov) {
  constexpr int MI = (BN == 128) ? 4 : 2;
  __shared__ u16 As[128 * 32];   // unpadded: global_load_lds is lane-linear
  __shared__ u16 Bs[BN * 32];
  const int tid = threadIdx.x;
  const int m0 = blockIdx.y * 128, n0 = blockIdx.x * BN;
  const bool is_c = (m0 < 1024);
  const u16* __restrict__ BT = is_c ? BTc : BTo;
  const int w = tid >> 6, lane = tid & 63, quad = lane >> 4, ln = lane & 15;
  const int wm = (BN == 128) ? (w >> 1) * 64 : w * 32;
  const int wn = (BN == 128) ? (w & 1) * 64 : 0;
  f32x4 acc[MI][4] = {};
  const int nkt = K >> 5;
  for (int kt = 0; kt < nkt; ++kt) {
    __syncthreads();
    {
      int c = tid;
      GLOAD_LDS16(A + (size_t)(m0 + (c >> 2)) * K + kt * 32 + (c & 3) * 8, As + c * 8);
      c = tid + 256;
      GLOAD_LDS16(A + (size_t)(m0 + (c >> 2)) * K + kt * 32 + (c & 3) * 8, As + c * 8);
      c = tid;
      GLOAD_LDS16(BT + (size_t)(n0 + (c >> 2)) * K + kt * 32 + (c & 3) * 8, Bs + c * 8);
      if (BN == 128) {
        c = tid + 256;
        GLOAD_LDS16(BT + (size_t)(n0 + (c >> 2)) * K + kt * 32 + (c & 3) * 8, Bs + c * 8);
      }
    }
    __syncthreads();
    bf16x8 a[MI], b[4];
#pragma unroll
    for (int i = 0; i < MI; ++i)
      a[i] = *(const bf16x8*)(As + (wm + i * 16 + ln) * 32 + quad * 8);
#pragma unroll
    for (int j = 0; j < 4; ++j)
      b[j] = *(const bf16x8*)(Bs + (wn + j * 16 + ln) * 32 + quad * 8);
#pragma unroll
    for (int i = 0; i < MI; ++i)
#pragma unroll
      for (int j = 0; j < 4; ++j) acc[i][j] = mfma16(a[i], b[j], acc[i][j]);
  }
  const float* bias = is_c ? bias_c : bias_o;
  const float* gate = is_c ? gate_c : gate_o;
  const float* x0 = is_c ? x0_c : x0_o;
#pragma unroll
  for (int i = 0; i < MI; ++i) {
#pragma unroll
    for (int j = 0; j < 4; ++j) {
#pragma unroll
      for (int r = 0; r < 4; ++r) {
        const int row = m0 + wm + i * 16 + quad * 4 + r;
        const int col = n0 + wn + j * 16 + ln;
        const float v = acc[i][j][r];
        if (mode == 0) {
          const int which = col >> 10, hh = (col & 1023) >> 6, dd = col & 63;
          u16* dst = (which == 0) ? oq : (which == 1) ? ok : ov;
          dst[((size_t)hh * 4096 + row) * 64 + dd] = f2bf(v);
        } else if (mode == 1) {
          const float xv = is_c ? x0[(size_t)row * 1024 + col]
                                : x0[(size_t)(row - 1024) * 1024 + col];
          ((u16*)outp)[(size_t)row * 1024 + col] = f2bf(xv + gate[col] * (v + bias[col]));
        } else if (mode == 2) {
          ((u16*)outp)[(size_t)row * N + col] = f2bf(gelu_tanh(v + bias[col]));
        } else {
          const float res = bf2f(x1[(size_t)row * 1024 + col]);
          const float val = res + gate[col] * (v + bias[col]);
          const size_t oidx = (row < 1024)
              ? (size_t)3145728 + (size_t)row * 1024 + col
              : (size_t)(row - 1024) * 1024 + col;
          ((float*)outp)[oidx] = val;
        }
      }
    }
  }
}

// ---- in-place rmsnorm+rope on head-major q,k; q pre-scaled by 0.125*log2(e) ----
__global__ __launch_bounds__(256) void qkprep_kernel(
    const float* __restrict__ pe,
    const float* __restrict__ qs_c, const float* __restrict__ ks_c,
    const float* __restrict__ qs_o, const float* __restrict__ ks_o,
    u16* __restrict__ qraw, u16* __restrict__ kraw) {
  const int l = blockIdx.x, tid = threadIdx.x;
  const bool is_c = l < 1024;
  const float* qs = is_c ? qs_c : qs_o;
  const float* ks = is_c ? ks_c : ks_o;
  const int head = tid >> 4, dd = (tid * 4) & 63;
  const size_t off = ((size_t)head * 4096 + l) * 64 + dd;
  const float* peb = pe + (size_t)l * 128 + (size_t)dd * 2;
  float4 pe0 = *(const float4*)(peb);
  float4 pe1 = *(const float4*)(peb + 4);
  {  // q (scaled into exp2-score domain)
    ushort4 raw = *(const ushort4*)(qraw + off);
    float x0 = bf2f(raw.x), x1v = bf2f(raw.y), x2 = bf2f(raw.z), x3 = bf2f(raw.w);
    float ssq = x0 * x0 + x1v * x1v + x2 * x2 + x3 * x3;
#pragma unroll
    for (int m = 1; m < 16; m <<= 1) ssq += __shfl_xor(ssq, m);
    float rms = rsqrtf(ssq * (1.0f / 64.0f) + 1e-6f) * 0.18033688011112042f;
    float n0 = x0 * rms * qs[dd + 0], n1 = x1v * rms * qs[dd + 1];
    float n2 = x2 * rms * qs[dd + 2], n3 = x3 * rms * qs[dd + 3];
    ushort4 o;
    o.x = f2bf(pe0.x * n0 + pe0.y * n1);
    o.y = f2bf(pe0.z * n0 + pe0.w * n1);
    o.z = f2bf(pe1.x * n2 + pe1.y * n3);
    o.w = f2bf(pe1.z * n2 + pe1.w * n3);
    *(ushort4*)(qraw + off) = o;
  }
  {  // k
    ushort4 raw = *(const ushort4*)(kraw + off);
    float x0 = bf2f(raw.x), x1v = bf2f(raw.y), x2 = bf2f(raw.z), x3 = bf2f(raw.w);
    float ssq = x0 * x0 + x1v * x1v + x2 * x2 + x3 * x3;
#pragma unroll
    for (int m = 1; m < 16; m <<= 1) ssq += __shfl_xor(ssq, m);
    float rms = rsqrtf(ssq * (1.0f / 64.0f) + 1e-6f);
    float n0 = x0 * rms * ks[dd + 0], n1 = x1v * rms * ks[dd + 1];
    float n2 = x2 * rms * ks[dd + 2], n3 = x3 * rms * ks[dd + 3];
    ushort4 o;
    o.x = f2bf(pe0.x * n0 + pe0.y * n1);
    o.y = f2bf(pe0.z * n0 + pe0.w * n1);
    o.z = f2bf(pe1.x * n2 + pe1.y * n3);
    o.w = f2bf(pe1.z * n2 + pe1.w * n3);
    *(ushort4*)(kraw + off) = o;
  }
}

// ---------------- one-shot V transpose: vraw[h][l][d] -> vt[h][d][l] ----------------
__global__ __launch_bounds__(256) void vtrans_kernel(
    const u16* __restrict__ vh, u16* __restrict__ vt) {
  const int h = blockIdx.y, k0 = blockIdx.x * 64;
  __shared__ u16 s[64 * 66];
  const int tid = threadIdx.x;
#pragma unroll
  for (int st = 0; st < 2; ++st) {
    int c = tid + st * 256;
    int row = c >> 3, off = (c & 7) << 3;
    ushort4 v0 = *(const ushort4*)(vh + ((size_t)h * 4096 + k0 + row) * 64 + off);
    ushort4 v1 = *(const ushort4*)(vh + ((size_t)h * 4096 + k0 + row) * 64 + off + 4);
    u16* p = s + row * 66 + off;
    p[0] = v0.x; p[1] = v0.y; p[2] = v0.z; p[3] = v0.w;
    p[4] = v1.x; p[5] = v1.y; p[6] = v1.z; p[7] = v1.w;
  }
  __syncthreads();
#pragma unroll
  for (int st = 0; st < 2; ++st) {
    int c = tid + st * 256;
    int dd = c >> 3, kk = (c & 7) << 3;
    ushort4 a, b;
    a.x = s[(kk + 0) * 66 + dd]; a.y = s[(kk + 1) * 66 + dd];
    a.z = s[(kk + 2) * 66 + dd]; a.w = s[(kk + 3) * 66 + dd];
    b.x = s[(kk + 4) * 66 + dd]; b.y = s[(kk + 5) * 66 + dd];
    b.z = s[(kk + 6) * 66 + dd]; b.w = s[(kk + 7) * 66 + dd];
    u16* o = vt + ((size_t)h * 64 + dd) * 4096 + k0 + kk;
    *(ushort4*)(o) = a;
    *(ushort4*)(o + 4) = b;
  }
}

// ---- one pipelined chunk: prefetch next K/V frags, then QK -> exp2 -> PV ----
__device__ __forceinline__ void attn_chunk(
    int cn, const u16* kbase, const u16* vbase, u16* Pw,
    int w, int ln, int quad,
    const bf16x8 (&bq)[4][2],
    bf16x8 (&akc)[2][2], bf16x8 (&bvc)[4],
    bf16x8 (&akn)[2][2], bf16x8 (&bvn)[4],
    f32x4 (&o)[4][4], float (&rs)[4]) {
  constexpr int L = 4096;
  if (cn < 32) {   // prefetch chunk cn into the other buffer (covers ~1 chunk of compute)
    const int kbn = cn * 128 + w * 32;
#pragma unroll
    for (int kk = 0; kk < 2; ++kk)
#pragma unroll
      for (int hf = 0; hf < 2; ++hf)
        akn[kk][hf] = *(const bf16x8*)(kbase + (size_t)(kbn + kk * 16 + ln) * 64 + hf * 32 + quad * 8);
#pragma unroll
    for (int jd = 0; jd < 4; ++jd)
      bvn[jd] = *(const bf16x8*)(vbase + (size_t)(jd * 16 + ln) * L + kbn + quad * 8);
  }
  f32x4 sT[2][4] = {};
#pragma unroll
  for (int kk = 0; kk < 2; ++kk)
#pragma unroll
    for (int nq = 0; nq < 4; ++nq) {
      sT[kk][nq] = mfma16(akc[kk][0], bq[nq][0], sT[kk][nq]);
      sT[kk][nq] = mfma16(akc[kk][1], bq[nq][1], sT[kk][nq]);
    }
  // raw v_exp_f32: scores pre-scaled by 0.125*log2e and bounded => no fixup needed
#pragma unroll
  for (int kk = 0; kk < 2; ++kk)
#pragma unroll
    for (int nq = 0; nq < 4; ++nq) {
      float p0 = fexp2(sT[kk][nq][0]);
      float p1 = fexp2(sT[kk][nq][1]);
      float p2 = fexp2(sT[kk][nq][2]);
      float p3 = fexp2(sT[kk][nq][3]);
      rs[nq] += (p0 + p1) + (p2 + p3);
      uint2 pk;
      pk.x = pack_bf2(p0, p1);
      pk.y = pack_bf2(p2, p3);
      *(uint2*)(Pw + (nq * 16 + ln) * 36 + kk * 16 + quad * 4) = pk;
    }
  bf16x8 ap[4];
#pragma unroll
  for (int nq = 0; nq < 4; ++nq)
    ap[nq] = ld8u(Pw + (nq * 16 + ln) * 36 + quad * 8);
#pragma unroll
  for (int jd = 0; jd < 4; ++jd)
#pragma unroll
    for (int nq = 0; nq < 4; ++nq)
      o[nq][jd] = mfma16(ap[nq], bvc[jd], o[nq][jd]);
}

// ---------------- flash attention v5: wave-partitioned keys + SW pipeline ----------------
__global__ __launch_bounds__(256) void attn_kernel(
    const u16* __restrict__ qh, const u16* __restrict__ kh,
    const u16* __restrict__ vt, u16* __restrict__ attn) {
  constexpr int L = 4096;
  const int h = blockIdx.y;
  const int q0 = blockIdx.x * 64;
  const int tid = threadIdx.x, w = tid >> 6, lane = tid & 63;
  const int quad = lane >> 4, ln = lane & 15;
  // LDS: per-wave P[64][36] u16; epilogue overlays bufA/bufB/rs4 on the dead P region
  __shared__ __align__(16) char smem[35840];
  u16* Pw = (u16*)(smem) + (size_t)w * 2304;
  float* bufA = (float*)smem;
  float* bufB = bufA + 4352;
  float* rs4 = bufB + 4352;

  bf16x8 bq[4][2];
  const u16* qbase = qh + ((size_t)h * L + q0) * 64;
#pragma unroll
  for (int nq = 0; nq < 4; ++nq)
#pragma unroll
    for (int hf = 0; hf < 2; ++hf)
      bq[nq][hf] = *(const bf16x8*)(qbase + (nq * 16 + ln) * 64 + hf * 32 + quad * 8);

  f32x4 o[4][4] = {};
  float rs[4] = {0.f, 0.f, 0.f, 0.f};
  const u16* kbase = kh + (size_t)h * L * 64;
  const u16* vbase = vt + (size_t)h * 64 * L;

  // double-buffered K/V register fragments; ping-pong via 2-unrolled loop
  bf16x8 akA[2][2], akB[2][2], bvA[4], bvB[4];
  {
    const int kb0 = w * 32;
#pragma unroll
    for (int kk = 0; kk < 2; ++kk)
#pragma unroll
      for (int hf = 0; hf < 2; ++hf)
        akA[kk][hf] = *(const bf16x8*)(kbase + (size_t)(kb0 + kk * 16 + ln) * 64 + hf * 32 + quad * 8);
#pragma unroll
    for (int jd = 0; jd < 4; ++jd)
      bvA[jd] = *(const bf16x8*)(vbase + (size_t)(jd * 16 + ln) * L + kb0 + quad * 8);
  }
  for (int c = 0; c < 32; c += 2) {
    attn_chunk(c + 1, kbase, vbase, Pw, w, ln, quad, bq, akA, bvA, akB, bvB, o, rs);
    attn_chunk(c + 2, kbase, vbase, Pw, w, ln, quad, bq, akB, bvB, akA, bvA, o, rs);
  }

  // ---- epilogue: cross-wave reduction of o and rs ----
  __syncthreads();   // all waves done with P region (bufs overlay it)
#pragma unroll
  for (int nq = 0; nq < 4; ++nq) {
    rs[nq] += __shfl_xor(rs[nq], 16);
    rs[nq] += __shfl_xor(rs[nq], 32);
  }
  if (quad == 0) {
#pragma unroll
    for (int nq = 0; nq < 4; ++nq) rs4[w * 64 + nq * 16 + ln] = rs[nq];
  }
  if (w == 1) {
#pragma unroll
    for (int nq = 0; nq < 4; ++nq)
#pragma unroll
      for (int jd = 0; jd < 4; ++jd)
        *(f32x4*)(bufA + (jd * 16 + ln) * 68 + nq * 16 + quad * 4) = o[nq][jd];
  }
  if (w == 3) {
#pragma unroll
    for (int nq = 0; nq < 4; ++nq)
#pragma unroll
      for (int jd = 0; jd < 4; ++jd)
        *(f32x4*)(bufB + (jd * 16 + ln) * 68 + nq * 16 + quad * 4) = o[nq][jd];
  }
  __syncthreads();
  if (w == 0) {
#pragma unroll
    for (int nq = 0; nq < 4; ++nq)
#pragma unroll
      for (int jd = 0; jd < 4; ++jd)
        o[nq][jd] += *(const f32x4*)(bufA + (jd * 16 + ln) * 68 + nq * 16 + quad * 4);
  }
  if (w == 2) {
#pragma unroll
    for (int nq = 0; nq < 4; ++nq)
#pragma unroll
      for (int jd = 0; jd < 4; ++jd)
        o[nq][jd] += *(const f32x4*)(bufB + (jd * 16 + ln) * 68 + nq * 16 + quad * 4);
  }
  __syncthreads();
  if (w == 2) {
#pragma unroll
    for (int nq = 0; nq < 4; ++nq)
#pragma unroll
      for (int jd = 0; jd < 4; ++jd)
        *(f32x4*)(bufA + (jd * 16 + ln) * 68 + nq * 16 + quad * 4) = o[nq][jd];
  }
  __syncthreads();
  if (w == 0) {
    float linv[4][4];
#pragma unroll
    for (int nq = 0; nq < 4; ++nq)
#pragma unroll
      for (int r = 0; r < 4; ++r) {
        const int qr = nq * 16 + quad * 4 + r;
        linv[nq][r] = 1.0f / (rs4[qr] + rs4[64 + qr] + rs4[128 + qr] + rs4[192 + qr]);
      }
#pragma unroll
    for (int nq = 0; nq < 4; ++nq)
#pragma unroll
      for (int jd = 0; jd < 4; ++jd) {
        f32x4 of = o[nq][jd];
        of += *(const f32x4*)(bufA + (jd * 16 + ln) * 68 + nq * 16 + quad * 4);
#pragma unroll
        for (int r = 0; r < 4; ++r) {
          const int row = q0 + nq * 16 + quad * 4 + r;
          attn[(size_t)row * 1024 + h * 64 + jd * 16 + ln] = f2bf(of[r] * linv[nq][r]);
        }
      }
  }
}

extern "C" void kernel_launch(void* const* d_in, const int* in_sizes, int n_in,
                              void* d_out, int out_size, void* d_ws, size_t ws_size,
                              hipStream_t stream) {
  (void)in_sizes; (void)n_in; (void)out_size; (void)ws_size;
  const float* obs         = (const float*)d_in[0];
  const float* cond        = (const float*)d_in[1];
  const float* vec         = (const float*)d_in[2];
  const float* pe          = (const float*)d_in[3];
  const float* obs_mod_w   = (const float*)d_in[4];
  const float* obs_mod_b   = (const float*)d_in[5];
  const float* obs_qkv_w   = (const float*)d_in[6];
  const float* obs_q_scale = (const float*)d_in[7];
  const float* obs_k_scale = (const float*)d_in[8];
  const float* obs_proj_w  = (const float*)d_in[9];
  const float* obs_proj_b  = (const float*)d_in[10];
  const float* obs_mlp_w1  = (const float*)d_in[11];
  const float* obs_mlp_b1  = (const float*)d_in[12];
  const float* obs_mlp_w2  = (const float*)d_in[13];
  const float* obs_mlp_b2  = (const float*)d_in[14];
  const float* cond_mod_w  = (const float*)d_in[15];
  const float* cond_mod_b  = (const float*)d_in[16];
  const float* cond_qkv_w  = (const float*)d_in[17];
  const float* cond_q_scale= (const float*)d_in[18];
  const float* cond_k_scale= (const float*)d_in[19];
  const float* cond_proj_w = (const float*)d_in[20];
  const float* cond_proj_b = (const float*)d_in[21];
  const float* cond_mlp_w1 = (const float*)d_in[22];
  const float* cond_mlp_b1 = (const float*)d_in[23];
  const float* cond_mlp_w2 = (const float*)d_in[24];
  const float* cond_mlp_b2 = (const float*)d_in[25];

  // Workspace (peak 64 MiB + 64 KiB — proven budget):
  //  [0,16M)   rotating bf16 weights: qkvT -> projT -> mlp1T -> mlp2T
  //  [16,24M)  xm -> x1(bf16)
  //  [24,32M)  qraw -> hm
  //  [32,40M)  kraw ─┐
  //  [40,48M)  vraw  ├─> g (32 MiB, spans 32..64M after all dead)
  //  [48,56M)  vt   ─┤
  //  [56,64M)  attn ─┘
  char* ws = (char*)d_ws;
  float* o_mod = (float*)ws;
  float* c_mod = o_mod + 6144;
  char* base = ws + 65536;
  u16* qkvT_c  = (u16*)base;
  u16* qkvT_o  = (u16*)(base + 6291456);
  u16* projT_c = (u16*)base;
  u16* projT_o = (u16*)(base + 2097152);
  u16* mlp1T_c = (u16*)base;
  u16* mlp1T_o = (u16*)(base + 8388608);
  u16* mlp2T_c = (u16*)base;
  u16* mlp2T_o = (u16*)(base + 8388608);
  u16* xm   = (u16*)(base + 16777216);
  u16* x1   = (u16*)(base + 16777216);
  u16* qraw = (u16*)(base + 25165824);
  u16* hm   = (u16*)(base + 25165824);
  u16* kraw = (u16*)(base + 33554432);
  u16* vraw = (u16*)(base + 41943040);
  u16* vt   = (u16*)(base + 50331648);
  u16* attn = (u16*)(base + 58720256);
  u16* g    = (u16*)(base + 33554432);

  modulation_kernel<<<192, 256, 0, stream>>>(vec, obs_mod_w, obs_mod_b,
                                             cond_mod_w, cond_mod_b, o_mod, c_mod);
  ln_mod_kernel<<<4096, 256, 0, stream>>>(cond, obs, c_mod, o_mod, 0, xm);
  transcast_kernel<<<dim3(48, 16, 2), 256, 0, stream>>>(cond_qkv_w, obs_qkv_w,
                                                        qkvT_c, qkvT_o, 1024, 3072);
  gemm_bf16<128><<<dim3(24, 32), 256, 0, stream>>>(xm, qkvT_c, qkvT_o, 3072, 1024, 0,
      nullptr, nullptr, nullptr, nullptr, nullptr, nullptr, nullptr, nullptr,
      qraw, kraw, vraw);
  qkprep_kernel<<<4096, 256, 0, stream>>>(pe, cond_q_scale, cond_k_scale,
                                          obs_q_scale, obs_k_scale, qraw, kraw);
  vtrans_kernel<<<dim3(64, 16), 256, 0, stream>>>(vraw, vt);
  attn_kernel<<<dim3(64, 16), 256, 0, stream>>>(qraw, kraw, vt, attn);
  transcast_kernel<<<dim3(16, 16, 2), 256, 0, stream>>>(cond_proj_w, obs_proj_w,
                                                        projT_c, projT_o, 1024, 1024);
  gemm_bf16<64><<<dim3(16, 32), 256, 0, stream>>>(attn, projT_c, projT_o, 1024, 1024, 1,
      cond_proj_b, obs_proj_b, c_mod + 2048, o_mod + 2048, cond, obs,
      nullptr, (void*)x1, nullptr, nullptr, nullptr);
  ln_mod_b_kernel<<<4096, 256, 0, stream>>>(x1, c_mod, o_mod, 3072, hm);
  transcast_kernel<<<dim3(64, 16, 2), 256, 0, stream>>>(cond_mlp_w1, obs_mlp_w1,
                                                        mlp1T_c, mlp1T_o, 1024, 4096);
  gemm_bf16<128><<<dim3(32, 32), 256, 0, stream>>>(hm, mlp1T_c, mlp1T_o, 4096, 1024, 2,
      cond_mlp_b1, obs_mlp_b1, nullptr, nullptr, nullptr, nullptr,
      nullptr, (void*)g, nullptr, nullptr, nullptr);
  transcast_kernel<<<dim3(16, 64, 2), 256, 0, stream>>>(cond_mlp_w2, obs_mlp_w2,
                                                        mlp2T_c, mlp2T_o, 4096, 1024);
  gemm_bf16<64><<<dim3(16, 32), 256, 0, stream>>>(g, mlp2T_c, mlp2T_o, 1024, 4096, 3,
      cond_mlp_b2, obs_mlp_b2, c_mod + 5120, o_mod + 5120, nullptr, nullptr,
      x1, d_out, nullptr, nullptr, nullptr);
}